// Round 9
// baseline (348.808 us; speedup 1.0000x reference)
//
#include <hip/hip_runtime.h>
#include <math.h>

typedef unsigned int uint;
typedef unsigned short ushort;
typedef unsigned char uchar;
typedef __attribute__((ext_vector_type(2))) float v2f;
typedef __attribute__((ext_vector_type(4))) _Float16 h4v;   // 8 B
typedef __attribute__((ext_vector_type(8))) _Float16 h8v;   // 16 B

#define S1 4.0f

template <bool HI>
__device__ inline v2f fp8x2f(uint u) {
    return __builtin_amdgcn_cvt_pk_f32_fp8((int)u, HI);
}

// ---- k_g1h: GEMM1 + edge histogram fused as independent block ranges ----
// blocks [0,GB): rec1[N] packed 128-B record {64B h1 fp8, 32B al1s, 32B al1d}
//                = x[N,128] @ W1[128,64]
// blocks [GB,GB+C): per-block LDS histogram of dst>>7 into counts
__global__ __launch_bounds__(256) void k_g1h(const float* __restrict__ x,
                                             const float* __restrict__ W1,
                                             const float* __restrict__ as1,
                                             const float* __restrict__ ad1,
                                             uchar* __restrict__ rec1,
                                             const int* __restrict__ dst,
                                             int* __restrict__ counts,
                                             int N, int E, int CH, int NB, int GB) {
    __shared__ float sB[128 * 64];
    __shared__ float sA[64 * 68];
    const int t = threadIdx.x;
    if (blockIdx.x >= GB) {
        // ---- histogram part ----
        int b = blockIdx.x - GB;
        int* hist = (int*)sB;
        for (int k = t; k < NB; k += 256) hist[k] = 0;
        __syncthreads();
        int e0 = b * CH;
        int e1 = e0 + CH; if (e1 > E) e1 = E;
        for (int e = e0 + t; e < e1; e += 256)
            atomicAdd(&hist[dst[e] >> 7], 1);
        __syncthreads();
        for (int k = t; k < NB; k += 256) counts[(size_t)b * NB + k] = hist[k];
        return;
    }
    // ---- gemm1 part ----
    const int n0 = blockIdx.x * 64;
    {
        const float4* w4 = (const float4*)W1;
        float4* s4 = (float4*)sB;
#pragma unroll
        for (int i = 0; i < 8; ++i) s4[t + i * 256] = w4[t + i * 256];
    }
    const int r0 = (t >> 3) * 2;
    const int c0 = (t & 7) * 8;   // head = t&7, channels c0..c0+7
    float acc0[8] = {0, 0, 0, 0, 0, 0, 0, 0};
    float acc1[8] = {0, 0, 0, 0, 0, 0, 0, 0};
    for (int kb = 0; kb < 2; ++kb) {
        __syncthreads();
#pragma unroll
        for (int i = 0; i < 4; ++i) {
            int idx = t + i * 256;
            int r = idx >> 4, kc = idx & 15;
            int n = n0 + r;
            float4 v = make_float4(0.f, 0.f, 0.f, 0.f);
            if (n < N) v = ((const float4*)x)[(size_t)n * 32 + kb * 16 + kc];
            *(float4*)&sA[r * 68 + kc * 4] = v;
        }
        __syncthreads();
        const float* bptr = &sB[kb * 64 * 64];
#pragma unroll 8
        for (int kk = 0; kk < 64; ++kk) {
            float a0 = sA[r0 * 68 + kk];
            float a1 = sA[(r0 + 1) * 68 + kk];
            const float* bp = &bptr[kk * 64 + c0];
            float4 b0 = *(const float4*)bp;
            float4 b1v = *(const float4*)(bp + 4);
            acc0[0] += a0 * b0.x; acc0[1] += a0 * b0.y; acc0[2] += a0 * b0.z; acc0[3] += a0 * b0.w;
            acc0[4] += a0 * b1v.x; acc0[5] += a0 * b1v.y; acc0[6] += a0 * b1v.z; acc0[7] += a0 * b1v.w;
            acc1[0] += a1 * b0.x; acc1[1] += a1 * b0.y; acc1[2] += a1 * b0.z; acc1[3] += a1 * b0.w;
            acc1[4] += a1 * b1v.x; acc1[5] += a1 * b1v.y; acc1[6] += a1 * b1v.z; acc1[7] += a1 * b1v.w;
        }
    }
    float ps0 = 0.f, pd0 = 0.f, ps1 = 0.f, pd1 = 0.f;
#pragma unroll
    for (int i = 0; i < 8; ++i) {
        float ws = as1[c0 + i], wd = ad1[c0 + i];
        ps0 += acc0[i] * ws; pd0 += acc0[i] * wd;
        ps1 += acc1[i] * ws; pd1 += acc1[i] * wd;
    }
    int n = n0 + r0;
    int head = t & 7;
    if (n < N) {
        int q0 = 0, q1 = 0;
        q0 = __builtin_amdgcn_cvt_pk_fp8_f32(acc0[0] * S1, acc0[1] * S1, q0, false);
        q0 = __builtin_amdgcn_cvt_pk_fp8_f32(acc0[2] * S1, acc0[3] * S1, q0, true);
        q1 = __builtin_amdgcn_cvt_pk_fp8_f32(acc0[4] * S1, acc0[5] * S1, q1, false);
        q1 = __builtin_amdgcn_cvt_pk_fp8_f32(acc0[6] * S1, acc0[7] * S1, q1, true);
        uint2 p; p.x = (uint)q0; p.y = (uint)q1;
        uchar* rp = rec1 + (size_t)n * 128;
        *(uint2*)(rp + c0) = p;
        *(float*)(rp + 64 + head * 4) = ps0;
        *(float*)(rp + 96 + head * 4) = pd0;
    }
    if (n + 1 < N) {
        int q0 = 0, q1 = 0;
        q0 = __builtin_amdgcn_cvt_pk_fp8_f32(acc1[0] * S1, acc1[1] * S1, q0, false);
        q0 = __builtin_amdgcn_cvt_pk_fp8_f32(acc1[2] * S1, acc1[3] * S1, q0, true);
        q1 = __builtin_amdgcn_cvt_pk_fp8_f32(acc1[4] * S1, acc1[5] * S1, q1, false);
        q1 = __builtin_amdgcn_cvt_pk_fp8_f32(acc1[6] * S1, acc1[7] * S1, q1, true);
        uint2 p; p.x = (uint)q0; p.y = (uint)q1;
        uchar* rp = rec1 + (size_t)(n + 1) * 128;
        *(uint2*)(rp + c0) = p;
        *(float*)(rp + 64 + head * 4) = ps1;
        *(float*)(rp + 96 + head * 4) = pd1;
    }
}

// ---- GEMM2: h2[N,128] (fp16, unscaled) = relu(x1pre(fp16)+b1) @ W2[64,128] ----
__global__ __launch_bounds__(256) void k_gemm2(const _Float16* __restrict__ x1pre,
                                               const float* __restrict__ W2,
                                               const float* __restrict__ b1,
                                               const float* __restrict__ as2,
                                               const float* __restrict__ ad2,
                                               _Float16* __restrict__ h2,
                                               float* __restrict__ al2s,
                                               float* __restrict__ al2d, int N) {
    __shared__ float sB[64 * 128];
    __shared__ float sA[64 * 68];
    const int t = threadIdx.x;
    const int n0 = blockIdx.x * 64;
    {
        const float4* w4 = (const float4*)W2;
        float4* s4 = (float4*)sB;
#pragma unroll
        for (int i = 0; i < 8; ++i) s4[t + i * 256] = w4[t + i * 256];
    }
#pragma unroll
    for (int i = 0; i < 4; ++i) {
        int idx = t + i * 256;
        int r = idx >> 4, kc = idx & 15;
        int n = n0 + r;
        float4 v = make_float4(0.f, 0.f, 0.f, 0.f);
        if (n < N) {
            h4v hv = *(const h4v*)(x1pre + (size_t)n * 64 + kc * 4);
            float4 bb = ((const float4*)b1)[kc];
            v.x = fmaxf((float)hv[0] + bb.x, 0.f);
            v.y = fmaxf((float)hv[1] + bb.y, 0.f);
            v.z = fmaxf((float)hv[2] + bb.z, 0.f);
            v.w = fmaxf((float)hv[3] + bb.w, 0.f);
        }
        *(float4*)&sA[r * 68 + kc * 4] = v;
    }
    __syncthreads();
    const int r0 = (t >> 3) * 2;
    const int cb = (t & 7) * 4;
    float acc0[16], acc1[16];
#pragma unroll
    for (int i = 0; i < 16; ++i) { acc0[i] = 0.f; acc1[i] = 0.f; }
#pragma unroll 4
    for (int k = 0; k < 64; ++k) {
        float a0 = sA[r0 * 68 + k];
        float a1 = sA[(r0 + 1) * 68 + k];
#pragma unroll
        for (int j = 0; j < 4; ++j) {
            float4 b = *(const float4*)&sB[k * 128 + cb + 32 * j];
            acc0[j * 4 + 0] += a0 * b.x; acc0[j * 4 + 1] += a0 * b.y;
            acc0[j * 4 + 2] += a0 * b.z; acc0[j * 4 + 3] += a0 * b.w;
            acc1[j * 4 + 0] += a1 * b.x; acc1[j * 4 + 1] += a1 * b.y;
            acc1[j * 4 + 2] += a1 * b.z; acc1[j * 4 + 3] += a1 * b.w;
        }
    }
    float ps0 = 0.f, pd0 = 0.f, ps1 = 0.f, pd1 = 0.f;
#pragma unroll
    for (int j = 0; j < 4; ++j)
#pragma unroll
        for (int i = 0; i < 4; ++i) {
            int cc = cb + 32 * j + i;
            float ws = as2[cc], wd = ad2[cc];
            ps0 += acc0[j * 4 + i] * ws; pd0 += acc0[j * 4 + i] * wd;
            ps1 += acc1[j * 4 + i] * ws; pd1 += acc1[j * 4 + i] * wd;
        }
#pragma unroll
    for (int off = 1; off < 8; off <<= 1) {
        ps0 += __shfl_xor(ps0, off); pd0 += __shfl_xor(pd0, off);
        ps1 += __shfl_xor(ps1, off); pd1 += __shfl_xor(pd1, off);
    }
    int n = n0 + r0;
    if (n < N) {
#pragma unroll
        for (int j = 0; j < 4; ++j) {
            h4v o;
            o[0] = (_Float16)acc0[j * 4 + 0];
            o[1] = (_Float16)acc0[j * 4 + 1];
            o[2] = (_Float16)acc0[j * 4 + 2];
            o[3] = (_Float16)acc0[j * 4 + 3];
            *(h4v*)&h2[(size_t)n * 128 + cb + 32 * j] = o;
        }
        if ((t & 7) == 0) { al2s[n] = ps0; al2d[n] = pd0; }
    }
    if (n + 1 < N) {
#pragma unroll
        for (int j = 0; j < 4; ++j) {
            h4v o;
            o[0] = (_Float16)acc1[j * 4 + 0];
            o[1] = (_Float16)acc1[j * 4 + 1];
            o[2] = (_Float16)acc1[j * 4 + 2];
            o[3] = (_Float16)acc1[j * 4 + 3];
            *(h4v*)&h2[(size_t)(n + 1) * 128 + cb + 32 * j] = o;
        }
        if ((t & 7) == 0) { al2s[n + 1] = ps1; al2d[n + 1] = pd1; }
    }
}

// ========== atomic-free CSR build (separate dispatches) ====

// pass B: per-bucket exclusive scan over blocks (one block per bucket)
__global__ __launch_bounds__(256) void k_bscan(int* __restrict__ counts,
                                               int* __restrict__ btot,
                                               int C, int NB) {
    __shared__ int sh[256];
    int t = threadIdx.x, k = blockIdx.x;
    int v[4];
#pragma unroll
    for (int i = 0; i < 4; ++i) {
        int b = t * 4 + i;
        v[i] = (b < C) ? counts[(size_t)b * NB + k] : 0;
    }
    int s = v[0] + v[1] + v[2] + v[3];
    sh[t] = s;
    __syncthreads();
    int accv = s;
    for (int off = 1; off < 256; off <<= 1) {
        int u = (t >= off) ? sh[t - off] : 0;
        __syncthreads();
        accv += u;
        sh[t] = accv;
        __syncthreads();
    }
    int excl = accv - s;
#pragma unroll
    for (int i = 0; i < 4; ++i) {
        int b = t * 4 + i;
        if (b < C) counts[(size_t)b * NB + k] = excl;
        excl += v[i];
    }
    if (t == 255) btot[k] = accv;
}

// pass D: scatter edges into bucket-sorted ebuf; bbase scan folded in
__global__ __launch_bounds__(256) void k_bucket(const int* __restrict__ src,
                                                const int* __restrict__ dst,
                                                const int* __restrict__ counts,
                                                const int* __restrict__ btot,
                                                int* __restrict__ bbase,
                                                int* __restrict__ ebuf,
                                                int E, int CH, int NB) {
    __shared__ int pos[784];
    __shared__ int sh[256];
    __shared__ int bb[784];
    int t = threadIdx.x, b = blockIdx.x;
    int v[4];
#pragma unroll
    for (int i = 0; i < 4; ++i) {
        int k = t * 4 + i;
        v[i] = (k < NB) ? btot[k] : 0;
    }
    int s = v[0] + v[1] + v[2] + v[3];
    sh[t] = s;
    __syncthreads();
    int accv = s;
    for (int off = 1; off < 256; off <<= 1) {
        int u = (t >= off) ? sh[t - off] : 0;
        __syncthreads();
        accv += u;
        sh[t] = accv;
        __syncthreads();
    }
    int excl = accv - s;
#pragma unroll
    for (int i = 0; i < 4; ++i) {
        int k = t * 4 + i;
        if (k < NB) bb[k] = excl;
        excl += v[i];
    }
    __syncthreads();
    for (int k = t; k < NB; k += 256)
        pos[k] = bb[k] + counts[(size_t)b * NB + k];
    if (b == 0) {
        for (int k = t; k < NB; k += 256) bbase[k] = bb[k];
        if (t == 0) bbase[NB] = E;
    }
    __syncthreads();
    int e0 = b * CH;
    int e1 = e0 + CH; if (e1 > E) e1 = E;
    for (int e = e0 + t; e < e1; e += 256) {
        int d = dst[e], s2 = src[e];
        int p = atomicAdd(&pos[d >> 7], 1);
        ebuf[p] = (int)((uint)s2 | ((uint)(d & 127) << 25));
    }
}

// pass E: per-bucket fine CSR
__global__ __launch_bounds__(256) void k_csr(const int* __restrict__ bbase,
                                             const int* __restrict__ ebuf,
                                             int* __restrict__ row_ptr,
                                             int* __restrict__ col,
                                             int N, int E) {
    __shared__ int cnt[128];
    __shared__ int fill[128];
    __shared__ int rowb[128];
    __shared__ int sh[256];
    int t = threadIdx.x, k = blockIdx.x;
    int lo = bbase[k], hi = bbase[k + 1];
    int nlo = k << 7;
    int nn = N - nlo; if (nn > 128) nn = 128;
    if (t < 128) { cnt[t] = 0; fill[t] = 0; }
    __syncthreads();
    for (int i = lo + t; i < hi; i += 256)
        atomicAdd(&cnt[((uint)ebuf[i]) >> 25], 1);
    __syncthreads();
    int v = (t < nn) ? (cnt[t] + 1) : 0;  // +1 self-loop slot
    sh[t] = v;
    __syncthreads();
    int accv = v;
    for (int off = 1; off < 256; off <<= 1) {
        int u = (t >= off) ? sh[t - off] : 0;
        __syncthreads();
        accv += u;
        sh[t] = accv;
        __syncthreads();
    }
    int fbase = lo + nlo;
    if (t < nn) {
        int rb = fbase + accv - v;
        rowb[t] = rb;
        row_ptr[nlo + t] = rb;
        col[rb + cnt[t]] = nlo + t;  // self-loop at end of row
    }
    if (k == 0 && t == 0) row_ptr[N] = E + N;
    __syncthreads();
    for (int i = lo + t; i < hi; i += 256) {
        uint e = (uint)ebuf[i];
        int j = (int)(e >> 25);
        int r = atomicAdd(&fill[j], 1);
        col[rowb[j] + r] = (int)(e & 0x1FFFFFFu);
    }
}

// ---- edge1: wave/node, shfl-free; ONE 128-B line per edge (packed rec1) ----
__global__ __launch_bounds__(256) void k_edge1(const uchar* __restrict__ rec1,
                                               const int* __restrict__ row_ptr,
                                               const int* __restrict__ col,
                                               _Float16* __restrict__ x1pre, int N) {
    int node = blockIdx.x * 4 + (threadIdx.x >> 6);
    if (node >= N) return;
    const int lane = threadIdx.x & 63;
    const int g = lane >> 4;       // edge subgroup 0..3
    const int k4 = lane & 15;      // channel quad (ch 4k4..4k4+3)
    const int hh = k4 >> 1;        // head of those channels
    const uint co = (uint)(k4 * 4);
    const uint ao = 64u + (uint)(hh * 4);
    const float a_dh = *(const float*)(rec1 + (((size_t)node) << 7) + 96 + hh * 4);
    const int s0 = row_ptr[node], s1 = row_ptr[node + 1];
    float den_part = 0.f;
    v2f accL = {0.f, 0.f};
    v2f accH = {0.f, 0.f};
    for (int base = s0; base < s1; base += 64) {
        int cnt = s1 - base; if (cnt > 64) cnt = 64;
        int cntR = (cnt + 3) & ~3;
        int i = 0;
        for (; i + 16 <= cntR; i += 16) {
            int eA = base + i + g, eB = eA + 4, eC = eA + 8, eD = eA + 12;
            int xD = eD < s1 ? eD : s1 - 1;       // only D can run past
            int cA = col[eA], cB = col[eB], cC = col[eC], cD = col[xD];
            const uchar* rA = rec1 + (((uint)cA) << 7);
            const uchar* rB = rec1 + (((uint)cB) << 7);
            const uchar* rC = rec1 + (((uint)cC) << 7);
            const uchar* rD = rec1 + (((uint)cD) << 7);
            uint hA = *(const uint*)(rA + co);
            uint hB = *(const uint*)(rB + co);
            uint hC = *(const uint*)(rC + co);
            uint hD = *(const uint*)(rD + co);
            float lA = *(const float*)(rA + ao) + a_dh;
            float lB = *(const float*)(rB + ao) + a_dh;
            float lC = *(const float*)(rC + ao) + a_dh;
            float lD = *(const float*)(rD + ao) + a_dh;
            lA = lA > 0.f ? lA : 0.2f * lA;
            lB = lB > 0.f ? lB : 0.2f * lB;
            lC = lC > 0.f ? lC : 0.2f * lC;
            lD = lD > 0.f ? lD : 0.2f * lD;
            float wA = __expf(lA);
            float wB = __expf(lB);
            float wC = __expf(lC);
            float wD = (eD < s1) ? __expf(lD) : 0.f;
            den_part += wA + wB + wC + wD;
            v2f wA2 = {wA, wA}, wB2 = {wB, wB}, wC2 = {wC, wC}, wD2 = {wD, wD};
            accL += wA2 * fp8x2f<false>(hA);
            accH += wA2 * fp8x2f<true>(hA);
            accL += wB2 * fp8x2f<false>(hB);
            accH += wB2 * fp8x2f<true>(hB);
            accL += wC2 * fp8x2f<false>(hC);
            accH += wC2 * fp8x2f<true>(hC);
            accL += wD2 * fp8x2f<false>(hD);
            accH += wD2 * fp8x2f<true>(hD);
        }
        int rem = cntR - i;
        if (rem & 8) {  // 8 edges
            int eA = base + i + g, eB = eA + 4;
            int xB = eB < s1 ? eB : s1 - 1;
            int cA = col[eA], cB = col[xB];
            const uchar* rA = rec1 + (((uint)cA) << 7);
            const uchar* rB = rec1 + (((uint)cB) << 7);
            uint hA = *(const uint*)(rA + co);
            uint hB = *(const uint*)(rB + co);
            float lA = *(const float*)(rA + ao) + a_dh;
            float lB = *(const float*)(rB + ao) + a_dh;
            lA = lA > 0.f ? lA : 0.2f * lA;
            lB = lB > 0.f ? lB : 0.2f * lB;
            float wA = __expf(lA);
            float wB = (eB < s1) ? __expf(lB) : 0.f;
            den_part += wA + wB;
            v2f wA2 = {wA, wA}, wB2 = {wB, wB};
            accL += wA2 * fp8x2f<false>(hA);
            accH += wA2 * fp8x2f<true>(hA);
            accL += wB2 * fp8x2f<false>(hB);
            accH += wB2 * fp8x2f<true>(hB);
            i += 8;
        }
        if (rem & 4) {  // 4 edges
            int eA = base + i + g;
            int xA = eA < s1 ? eA : s1 - 1;
            int cA = col[xA];
            const uchar* rA = rec1 + (((uint)cA) << 7);
            uint hA = *(const uint*)(rA + co);
            float lA = *(const float*)(rA + ao) + a_dh;
            lA = lA > 0.f ? lA : 0.2f * lA;
            float wA = (eA < s1) ? __expf(lA) : 0.f;
            den_part += wA;
            v2f wA2 = {wA, wA};
            accL += wA2 * fp8x2f<false>(hA);
            accH += wA2 * fp8x2f<true>(hA);
        }
    }
    float a0 = accL.x, a1 = accL.y, a2 = accH.x, a3 = accH.y;
    a0 += __shfl_xor(a0, 16); a0 += __shfl_xor(a0, 32);
    a1 += __shfl_xor(a1, 16); a1 += __shfl_xor(a1, 32);
    a2 += __shfl_xor(a2, 16); a2 += __shfl_xor(a2, 32);
    a3 += __shfl_xor(a3, 16); a3 += __shfl_xor(a3, 32);
    den_part += __shfl_xor(den_part, 16);
    den_part += __shfl_xor(den_part, 32);   // per-lane den for head hh
    if (lane < 16) {
        float invd = 1.f / (den_part * S1);
        h4v o;
        o[0] = (_Float16)(a0 * invd);
        o[1] = (_Float16)(a1 * invd);
        o[2] = (_Float16)(a2 * invd);
        o[3] = (_Float16)(a3 * invd);
        *(h4v*)(x1pre + (size_t)node * 64 + co) = o;
    }
}

// ---- edge2: wave/node; fp16 H-table gathers, packed fp16 accumulation ----
__global__ __launch_bounds__(256) void k_edge2(const _Float16* __restrict__ h2,
                                               const float* __restrict__ al2s,
                                               const float* __restrict__ al2d,
                                               const int* __restrict__ row_ptr,
                                               const int* __restrict__ col,
                                               _Float16* __restrict__ x2, int N) {
    int node = blockIdx.x * 4 + (threadIdx.x >> 6);
    if (node >= N) return;
    const int lane = threadIdx.x & 63;
    const int g = lane >> 4;    // edge group 0..3
    const int k8 = lane & 15;   // channel oct (ch 8k8..8k8+7 of 128)
    const uint co = (uint)(k8 * 8);     // in _Float16 elements
    const float a_d = al2d[node];
    const int s0 = row_ptr[node], s1 = row_ptr[node + 1];
    h8v acc8 = {(_Float16)0.f, (_Float16)0.f, (_Float16)0.f, (_Float16)0.f,
                (_Float16)0.f, (_Float16)0.f, (_Float16)0.f, (_Float16)0.f};
    float den_part = 0.f;
    for (int base = s0; base < s1; base += 64) {
        int cnt = s1 - base; if (cnt > 64) cnt = 64;
        int cntR = (cnt + 3) & ~3;
        int i = 0;
        for (; i + 16 <= cntR; i += 16) {
            int eA = base + i + g, eB = eA + 4, eC = eA + 8, eD = eA + 12;
            int xD = eD < s1 ? eD : s1 - 1;
            int cA = col[eA], cB = col[eB], cC = col[eC], cD = col[xD];
            h8v hA = *(const h8v*)(h2 + ((((size_t)(uint)cA) << 7) + co));
            h8v hB = *(const h8v*)(h2 + ((((size_t)(uint)cB) << 7) + co));
            h8v hC = *(const h8v*)(h2 + ((((size_t)(uint)cC) << 7) + co));
            h8v hD = *(const h8v*)(h2 + ((((size_t)(uint)cD) << 7) + co));
            float lA = al2s[(uint)cA] + a_d;
            float lB = al2s[(uint)cB] + a_d;
            float lC = al2s[(uint)cC] + a_d;
            float lD = al2s[(uint)cD] + a_d;
            lA = lA > 0.f ? lA : 0.2f * lA;
            lB = lB > 0.f ? lB : 0.2f * lB;
            lC = lC > 0.f ? lC : 0.2f * lC;
            lD = lD > 0.f ? lD : 0.2f * lD;
            float wA = __expf(lA);
            float wB = __expf(lB);
            float wC = __expf(lC);
            float wD = (eD < s1) ? __expf(lD) : 0.f;
            den_part += wA + wB + wC + wD;
            _Float16 fA = (_Float16)wA, fB = (_Float16)wB;
            _Float16 fC = (_Float16)wC, fD = (_Float16)wD;
            h8v wA8 = {fA, fA, fA, fA, fA, fA, fA, fA};
            h8v wB8 = {fB, fB, fB, fB, fB, fB, fB, fB};
            h8v wC8 = {fC, fC, fC, fC, fC, fC, fC, fC};
            h8v wD8 = {fD, fD, fD, fD, fD, fD, fD, fD};
            acc8 += hA * wA8;
            acc8 += hB * wB8;
            acc8 += hC * wC8;
            acc8 += hD * wD8;
        }
        int rem = cntR - i;
        if (rem & 8) {
            int eA = base + i + g, eB = eA + 4;
            int xB = eB < s1 ? eB : s1 - 1;
            int cA = col[eA], cB = col[xB];
            h8v hA = *(const h8v*)(h2 + ((((size_t)(uint)cA) << 7) + co));
            h8v hB = *(const h8v*)(h2 + ((((size_t)(uint)cB) << 7) + co));
            float lA = al2s[(uint)cA] + a_d;
            float lB = al2s[(uint)cB] + a_d;
            lA = lA > 0.f ? lA : 0.2f * lA;
            lB = lB > 0.f ? lB : 0.2f * lB;
            float wA = __expf(lA);
            float wB = (eB < s1) ? __expf(lB) : 0.f;
            den_part += wA + wB;
            _Float16 fA = (_Float16)wA, fB = (_Float16)wB;
            h8v wA8 = {fA, fA, fA, fA, fA, fA, fA, fA};
            h8v wB8 = {fB, fB, fB, fB, fB, fB, fB, fB};
            acc8 += hA * wA8;
            acc8 += hB * wB8;
            i += 8;
        }
        if (rem & 4) {
            int eA = base + i + g;
            int xA = eA < s1 ? eA : s1 - 1;
            int cA = col[xA];
            h8v hA = *(const h8v*)(h2 + ((((size_t)(uint)cA) << 7) + co));
            float lA = al2s[(uint)cA] + a_d;
            lA = lA > 0.f ? lA : 0.2f * lA;
            float wA = (eA < s1) ? __expf(lA) : 0.f;
            den_part += wA;
            _Float16 fA = (_Float16)wA;
            h8v wA8 = {fA, fA, fA, fA, fA, fA, fA, fA};
            acc8 += hA * wA8;
        }
    }
    den_part += __shfl_xor(den_part, 16);
    den_part += __shfl_xor(den_part, 32);
    float r0 = (float)acc8[0], r1 = (float)acc8[1], r2 = (float)acc8[2], r3 = (float)acc8[3];
    float r4 = (float)acc8[4], r5 = (float)acc8[5], r6 = (float)acc8[6], r7 = (float)acc8[7];
    r0 += __shfl_xor(r0, 16); r0 += __shfl_xor(r0, 32);
    r1 += __shfl_xor(r1, 16); r1 += __shfl_xor(r1, 32);
    r2 += __shfl_xor(r2, 16); r2 += __shfl_xor(r2, 32);
    r3 += __shfl_xor(r3, 16); r3 += __shfl_xor(r3, 32);
    r4 += __shfl_xor(r4, 16); r4 += __shfl_xor(r4, 32);
    r5 += __shfl_xor(r5, 16); r5 += __shfl_xor(r5, 32);
    r6 += __shfl_xor(r6, 16); r6 += __shfl_xor(r6, 32);
    r7 += __shfl_xor(r7, 16); r7 += __shfl_xor(r7, 32);
    if (lane < 16) {
        float invd = 1.f / den_part;
        h8v o;
        o[0] = (_Float16)(r0 * invd);
        o[1] = (_Float16)(r1 * invd);
        o[2] = (_Float16)(r2 * invd);
        o[3] = (_Float16)(r3 * invd);
        o[4] = (_Float16)(r4 * invd);
        o[5] = (_Float16)(r5 * invd);
        o[6] = (_Float16)(r6 * invd);
        o[7] = (_Float16)(r7 * invd);
        *(h8v*)(x2 + (size_t)node * 128 + co) = o;
    }
}

// ---- k_poolfc: one block per graph; batch sorted -> binary-search node range,
// mean-pool in registers (no atomics, no memset), then wave 0 does FC+logsoftmax.
__global__ __launch_bounds__(128) void k_poolfc(const _Float16* __restrict__ x2,
                                                const int* __restrict__ batch,
                                                const float* __restrict__ b2,
                                                const float* __restrict__ fcw,
                                                const float* __restrict__ fcb,
                                                float* __restrict__ out,
                                                int N, int G) {
    __shared__ float sp[128];
    const int g = blockIdx.x;
    const int t = threadIdx.x;
    int lo = 0, hi = N;
    while (lo < hi) { int m = (lo + hi) >> 1; if (batch[m] < g) lo = m + 1; else hi = m; }
    const int s = lo;
    hi = N;
    while (lo < hi) { int m = (lo + hi) >> 1; if (batch[m] < g + 1) lo = m + 1; else hi = m; }
    const int e = lo;
    float a0 = 0.f, a1 = 0.f, a2 = 0.f, a3 = 0.f;
    int n = s;
    for (; n + 4 <= e; n += 4) {
        a0 += (float)x2[(size_t)(n + 0) * 128 + t];
        a1 += (float)x2[(size_t)(n + 1) * 128 + t];
        a2 += (float)x2[(size_t)(n + 2) * 128 + t];
        a3 += (float)x2[(size_t)(n + 3) * 128 + t];
    }
    for (; n < e; ++n) a0 += (float)x2[(size_t)n * 128 + t];
    float inv = 1.f / fmaxf((float)(e - s), 1.f);
    sp[t] = (a0 + a1 + a2 + a3) * inv + b2[t];
    __syncthreads();
    if (t < 64) {
        int c = t;
        float2 p = ((const float2*)sp)[c];
        float l[10];
#pragma unroll
        for (int j = 0; j < 10; ++j)
            l[j] = p.x * fcw[(2 * c) * 10 + j] + p.y * fcw[(2 * c + 1) * 10 + j];
#pragma unroll
        for (int j = 0; j < 10; ++j)
            for (int off = 1; off < 64; off <<= 1) l[j] += __shfl_xor(l[j], off);
        if (c == 0) {
            float lj[10];
            float m = -1e30f;
#pragma unroll
            for (int j = 0; j < 10; ++j) {
                lj[j] = l[j] + fcb[j];
                m = fmaxf(m, lj[j]);
            }
            float sde = 0.f;
#pragma unroll
            for (int j = 0; j < 10; ++j) sde += expf(lj[j] - m);
            float ls = logf(sde);
#pragma unroll
            for (int j = 0; j < 10; ++j) out[(size_t)g * 10 + j] = lj[j] - m - ls;
        }
    }
}

extern "C" void kernel_launch(void* const* d_in, const int* in_sizes, int n_in,
                              void* d_out, int out_size, void* d_ws, size_t ws_size,
                              hipStream_t stream) {
    const float* x     = (const float*)d_in[0];
    const int*   ei    = (const int*)d_in[1];
    const int*   batch = (const int*)d_in[2];
    const float* W1    = (const float*)d_in[3];
    const float* as1   = (const float*)d_in[4];
    const float* ad1   = (const float*)d_in[5];
    const float* b1    = (const float*)d_in[6];
    const float* W2    = (const float*)d_in[7];
    const float* as2   = (const float*)d_in[8];
    const float* ad2   = (const float*)d_in[9];
    const float* b2    = (const float*)d_in[10];
    const float* fcw   = (const float*)d_in[11];
    const float* fcb   = (const float*)d_in[12];
    float* out = (float*)d_out;

    const int N = in_sizes[0] / 128;
    const int E = in_sizes[1] / 2;
    const int G = out_size / 10;
    const int* srcp = ei;
    const int* dstp = ei + E;

    // workspace (float units):
    //   [0,32N)     rec1 (N x 128B packed) -- dead after k_edge1
    //   [32N,64N)   x1pre (fp16 N*64)      -- dead after k_gemm2
    //   [0,64N)     x2 (fp16 N*128) -- aliases dead rec1/x1pre
    //   [128N,192N) h2 (fp16 N*128, 25.6 MB)
    //   [192N,193N) al2s  [193N,194N) al2d
    //   [194N,...)  int region (ebuf, counts, btot, bbase, row_ptr, col)
    float* wf = (float*)d_ws;
    uchar*    rec1  = (uchar*)wf;
    _Float16* x1pre = (_Float16*)(wf + (size_t)N * 32);
    _Float16* x2    = (_Float16*)wf;
    _Float16* h2    = (_Float16*)(wf + (size_t)N * 128);
    float* al2s_  = wf + (size_t)N * 192;
    float* al2d_  = wf + (size_t)N * 193;

    const int NB = (N + 127) >> 7;      // 782 buckets (requires NB <= 784)
    const int C  = 256;                 // histogram/scatter blocks (longer runs)
    const int CH = (E + C - 1) / C;     // edges per block

    int* ib = (int*)(((uintptr_t)(wf + (size_t)N * 194) + 15) & ~(uintptr_t)15);
    int* ebuf    = ib;                              // [E] packed src|((dst&127)<<25)
    int* counts  = ib + (size_t)E;                  // [C*NB]
    int* btot    = counts + (size_t)C * NB;         // [NB]
    int* bbase   = btot + NB;                       // [NB+1]
    int* row_ptr = bbase + NB + 1;                  // [N+1]
    int* col     = row_ptr + N + 1;                 // [E+N]

    const int nb64 = (N + 63) / 64;
    const int nb4  = (N + 3) / 4;

    k_g1h<<<nb64 + C, 256, 0, stream>>>(x, W1, as1, ad1, rec1, dstp, counts,
                                        N, E, CH, NB, nb64);
    k_bscan<<<NB, 256, 0, stream>>>(counts, btot, C, NB);
    k_bucket<<<C, 256, 0, stream>>>(srcp, dstp, counts, btot, bbase, ebuf, E, CH, NB);
    k_csr<<<NB, 256, 0, stream>>>(bbase, ebuf, row_ptr, col, N, E);
    k_edge1<<<nb4, 256, 0, stream>>>(rec1, row_ptr, col, x1pre, N);
    k_gemm2<<<nb64, 256, 0, stream>>>(x1pre, W2, b1, as2, ad2, h2, al2s_, al2d_, N);
    k_edge2<<<nb4, 256, 0, stream>>>(h2, al2s_, al2d_, row_ptr, col, x2, N);
    k_poolfc<<<G, 128, 0, stream>>>(x2, batch, b2, fcw, fcb, out, N, G);
}

// Round 10
// 327.975 us; speedup vs baseline: 1.0635x; 1.0635x over previous
//
#include <hip/hip_runtime.h>
#include <math.h>

typedef unsigned int uint;
typedef unsigned short ushort;
typedef unsigned char uchar;
typedef __attribute__((ext_vector_type(2))) float v2f;
typedef __attribute__((ext_vector_type(4))) _Float16 h4v;   // 8 B
typedef __attribute__((ext_vector_type(8))) _Float16 h8v;   // 16 B

#define S1 4.0f
#define S2 16.0f

template <bool HI>
__device__ inline v2f fp8x2f(uint u) {
    return __builtin_amdgcn_cvt_pk_f32_fp8((int)u, HI);
}

// ---- k_g1h: GEMM1 + edge histogram fused as independent block ranges ----
// blocks [0,GB): rec1[N] packed 128-B record {64B h1 fp8, 32B al1s, 32B al1d}
//                = x[N,128] @ W1[128,64]
// blocks [GB,GB+C): per-block LDS histogram of dst>>7 into counts
__global__ __launch_bounds__(256) void k_g1h(const float* __restrict__ x,
                                             const float* __restrict__ W1,
                                             const float* __restrict__ as1,
                                             const float* __restrict__ ad1,
                                             uchar* __restrict__ rec1,
                                             const int* __restrict__ dst,
                                             int* __restrict__ counts,
                                             int N, int E, int CH, int NB, int GB) {
    __shared__ float sB[128 * 64];
    __shared__ float sA[64 * 68];
    const int t = threadIdx.x;
    if (blockIdx.x >= GB) {
        // ---- histogram part ----
        int b = blockIdx.x - GB;
        int* hist = (int*)sB;
        for (int k = t; k < NB; k += 256) hist[k] = 0;
        __syncthreads();
        int e0 = b * CH;
        int e1 = e0 + CH; if (e1 > E) e1 = E;
        for (int e = e0 + t; e < e1; e += 256)
            atomicAdd(&hist[dst[e] >> 7], 1);
        __syncthreads();
        for (int k = t; k < NB; k += 256) counts[(size_t)b * NB + k] = hist[k];
        return;
    }
    // ---- gemm1 part ----
    const int n0 = blockIdx.x * 64;
    {
        const float4* w4 = (const float4*)W1;
        float4* s4 = (float4*)sB;
#pragma unroll
        for (int i = 0; i < 8; ++i) s4[t + i * 256] = w4[t + i * 256];
    }
    const int r0 = (t >> 3) * 2;
    const int c0 = (t & 7) * 8;   // head = t&7, channels c0..c0+7
    float acc0[8] = {0, 0, 0, 0, 0, 0, 0, 0};
    float acc1[8] = {0, 0, 0, 0, 0, 0, 0, 0};
    for (int kb = 0; kb < 2; ++kb) {
        __syncthreads();
#pragma unroll
        for (int i = 0; i < 4; ++i) {
            int idx = t + i * 256;
            int r = idx >> 4, kc = idx & 15;
            int n = n0 + r;
            float4 v = make_float4(0.f, 0.f, 0.f, 0.f);
            if (n < N) v = ((const float4*)x)[(size_t)n * 32 + kb * 16 + kc];
            *(float4*)&sA[r * 68 + kc * 4] = v;
        }
        __syncthreads();
        const float* bptr = &sB[kb * 64 * 64];
#pragma unroll 8
        for (int kk = 0; kk < 64; ++kk) {
            float a0 = sA[r0 * 68 + kk];
            float a1 = sA[(r0 + 1) * 68 + kk];
            const float* bp = &bptr[kk * 64 + c0];
            float4 b0 = *(const float4*)bp;
            float4 b1v = *(const float4*)(bp + 4);
            acc0[0] += a0 * b0.x; acc0[1] += a0 * b0.y; acc0[2] += a0 * b0.z; acc0[3] += a0 * b0.w;
            acc0[4] += a0 * b1v.x; acc0[5] += a0 * b1v.y; acc0[6] += a0 * b1v.z; acc0[7] += a0 * b1v.w;
            acc1[0] += a1 * b0.x; acc1[1] += a1 * b0.y; acc1[2] += a1 * b0.z; acc1[3] += a1 * b0.w;
            acc1[4] += a1 * b1v.x; acc1[5] += a1 * b1v.y; acc1[6] += a1 * b1v.z; acc1[7] += a1 * b1v.w;
        }
    }
    float ps0 = 0.f, pd0 = 0.f, ps1 = 0.f, pd1 = 0.f;
#pragma unroll
    for (int i = 0; i < 8; ++i) {
        float ws = as1[c0 + i], wd = ad1[c0 + i];
        ps0 += acc0[i] * ws; pd0 += acc0[i] * wd;
        ps1 += acc1[i] * ws; pd1 += acc1[i] * wd;
    }
    int n = n0 + r0;
    int head = t & 7;
    if (n < N) {
        int q0 = 0, q1 = 0;
        q0 = __builtin_amdgcn_cvt_pk_fp8_f32(acc0[0] * S1, acc0[1] * S1, q0, false);
        q0 = __builtin_amdgcn_cvt_pk_fp8_f32(acc0[2] * S1, acc0[3] * S1, q0, true);
        q1 = __builtin_amdgcn_cvt_pk_fp8_f32(acc0[4] * S1, acc0[5] * S1, q1, false);
        q1 = __builtin_amdgcn_cvt_pk_fp8_f32(acc0[6] * S1, acc0[7] * S1, q1, true);
        uint2 p; p.x = (uint)q0; p.y = (uint)q1;
        uchar* rp = rec1 + (size_t)n * 128;
        *(uint2*)(rp + c0) = p;
        *(float*)(rp + 64 + head * 4) = ps0;
        *(float*)(rp + 96 + head * 4) = pd0;
    }
    if (n + 1 < N) {
        int q0 = 0, q1 = 0;
        q0 = __builtin_amdgcn_cvt_pk_fp8_f32(acc1[0] * S1, acc1[1] * S1, q0, false);
        q0 = __builtin_amdgcn_cvt_pk_fp8_f32(acc1[2] * S1, acc1[3] * S1, q0, true);
        q1 = __builtin_amdgcn_cvt_pk_fp8_f32(acc1[4] * S1, acc1[5] * S1, q1, false);
        q1 = __builtin_amdgcn_cvt_pk_fp8_f32(acc1[6] * S1, acc1[7] * S1, q1, true);
        uint2 p; p.x = (uint)q0; p.y = (uint)q1;
        uchar* rp = rec1 + (size_t)(n + 1) * 128;
        *(uint2*)(rp + c0) = p;
        *(float*)(rp + 64 + head * 4) = ps1;
        *(float*)(rp + 96 + head * 4) = pd1;
    }
}

// ---- GEMM2: h2f8[N,128](fp8,S2) = relu(x1pre(fp16)+b1) @ W2[64,128], fused al2 ----
__global__ __launch_bounds__(256) void k_gemm2(const _Float16* __restrict__ x1pre,
                                               const float* __restrict__ W2,
                                               const float* __restrict__ b1,
                                               const float* __restrict__ as2,
                                               const float* __restrict__ ad2,
                                               uchar* __restrict__ h2f8,
                                               float* __restrict__ al2s,
                                               float* __restrict__ al2d, int N) {
    __shared__ float sB[64 * 128];
    __shared__ float sA[64 * 68];
    const int t = threadIdx.x;
    const int n0 = blockIdx.x * 64;
    {
        const float4* w4 = (const float4*)W2;
        float4* s4 = (float4*)sB;
#pragma unroll
        for (int i = 0; i < 8; ++i) s4[t + i * 256] = w4[t + i * 256];
    }
#pragma unroll
    for (int i = 0; i < 4; ++i) {
        int idx = t + i * 256;
        int r = idx >> 4, kc = idx & 15;
        int n = n0 + r;
        float4 v = make_float4(0.f, 0.f, 0.f, 0.f);
        if (n < N) {
            h4v hv = *(const h4v*)(x1pre + (size_t)n * 64 + kc * 4);
            float4 bb = ((const float4*)b1)[kc];
            v.x = fmaxf((float)hv[0] + bb.x, 0.f);
            v.y = fmaxf((float)hv[1] + bb.y, 0.f);
            v.z = fmaxf((float)hv[2] + bb.z, 0.f);
            v.w = fmaxf((float)hv[3] + bb.w, 0.f);
        }
        *(float4*)&sA[r * 68 + kc * 4] = v;
    }
    __syncthreads();
    const int r0 = (t >> 3) * 2;
    const int cb = (t & 7) * 4;
    float acc0[16], acc1[16];
#pragma unroll
    for (int i = 0; i < 16; ++i) { acc0[i] = 0.f; acc1[i] = 0.f; }
#pragma unroll 4
    for (int k = 0; k < 64; ++k) {
        float a0 = sA[r0 * 68 + k];
        float a1 = sA[(r0 + 1) * 68 + k];
#pragma unroll
        for (int j = 0; j < 4; ++j) {
            float4 b = *(const float4*)&sB[k * 128 + cb + 32 * j];
            acc0[j * 4 + 0] += a0 * b.x; acc0[j * 4 + 1] += a0 * b.y;
            acc0[j * 4 + 2] += a0 * b.z; acc0[j * 4 + 3] += a0 * b.w;
            acc1[j * 4 + 0] += a1 * b.x; acc1[j * 4 + 1] += a1 * b.y;
            acc1[j * 4 + 2] += a1 * b.z; acc1[j * 4 + 3] += a1 * b.w;
        }
    }
    float ps0 = 0.f, pd0 = 0.f, ps1 = 0.f, pd1 = 0.f;
#pragma unroll
    for (int j = 0; j < 4; ++j)
#pragma unroll
        for (int i = 0; i < 4; ++i) {
            int cc = cb + 32 * j + i;
            float ws = as2[cc], wd = ad2[cc];
            ps0 += acc0[j * 4 + i] * ws; pd0 += acc0[j * 4 + i] * wd;
            ps1 += acc1[j * 4 + i] * ws; pd1 += acc1[j * 4 + i] * wd;
        }
#pragma unroll
    for (int off = 1; off < 8; off <<= 1) {
        ps0 += __shfl_xor(ps0, off); pd0 += __shfl_xor(pd0, off);
        ps1 += __shfl_xor(ps1, off); pd1 += __shfl_xor(pd1, off);
    }
    int n = n0 + r0;
    if (n < N) {
#pragma unroll
        for (int j = 0; j < 4; ++j) {
            int q = 0;
            q = __builtin_amdgcn_cvt_pk_fp8_f32(acc0[j * 4 + 0] * S2, acc0[j * 4 + 1] * S2, q, false);
            q = __builtin_amdgcn_cvt_pk_fp8_f32(acc0[j * 4 + 2] * S2, acc0[j * 4 + 3] * S2, q, true);
            *(uint*)&h2f8[(size_t)n * 128 + cb + 32 * j] = (uint)q;
        }
        if ((t & 7) == 0) { al2s[n] = ps0; al2d[n] = pd0; }
    }
    if (n + 1 < N) {
#pragma unroll
        for (int j = 0; j < 4; ++j) {
            int q = 0;
            q = __builtin_amdgcn_cvt_pk_fp8_f32(acc1[j * 4 + 0] * S2, acc1[j * 4 + 1] * S2, q, false);
            q = __builtin_amdgcn_cvt_pk_fp8_f32(acc1[j * 4 + 2] * S2, acc1[j * 4 + 3] * S2, q, true);
            *(uint*)&h2f8[(size_t)(n + 1) * 128 + cb + 32 * j] = (uint)q;
        }
        if ((t & 7) == 0) { al2s[n + 1] = ps1; al2d[n + 1] = pd1; }
    }
}

// ========== atomic-free CSR build (separate dispatches) ====

// pass B: per-bucket exclusive scan over blocks (one block per bucket)
__global__ __launch_bounds__(256) void k_bscan(int* __restrict__ counts,
                                               int* __restrict__ btot,
                                               int C, int NB) {
    __shared__ int sh[256];
    int t = threadIdx.x, k = blockIdx.x;
    int v[4];
#pragma unroll
    for (int i = 0; i < 4; ++i) {
        int b = t * 4 + i;
        v[i] = (b < C) ? counts[(size_t)b * NB + k] : 0;
    }
    int s = v[0] + v[1] + v[2] + v[3];
    sh[t] = s;
    __syncthreads();
    int accv = s;
    for (int off = 1; off < 256; off <<= 1) {
        int u = (t >= off) ? sh[t - off] : 0;
        __syncthreads();
        accv += u;
        sh[t] = accv;
        __syncthreads();
    }
    int excl = accv - s;
#pragma unroll
    for (int i = 0; i < 4; ++i) {
        int b = t * 4 + i;
        if (b < C) counts[(size_t)b * NB + k] = excl;
        excl += v[i];
    }
    if (t == 255) btot[k] = accv;
}

// pass D: scatter edges into bucket-sorted ebuf; bbase scan folded in
__global__ __launch_bounds__(256) void k_bucket(const int* __restrict__ src,
                                                const int* __restrict__ dst,
                                                const int* __restrict__ counts,
                                                const int* __restrict__ btot,
                                                int* __restrict__ bbase,
                                                int* __restrict__ ebuf,
                                                int E, int CH, int NB) {
    __shared__ int pos[784];
    __shared__ int sh[256];
    __shared__ int bb[784];
    int t = threadIdx.x, b = blockIdx.x;
    int v[4];
#pragma unroll
    for (int i = 0; i < 4; ++i) {
        int k = t * 4 + i;
        v[i] = (k < NB) ? btot[k] : 0;
    }
    int s = v[0] + v[1] + v[2] + v[3];
    sh[t] = s;
    __syncthreads();
    int accv = s;
    for (int off = 1; off < 256; off <<= 1) {
        int u = (t >= off) ? sh[t - off] : 0;
        __syncthreads();
        accv += u;
        sh[t] = accv;
        __syncthreads();
    }
    int excl = accv - s;
#pragma unroll
    for (int i = 0; i < 4; ++i) {
        int k = t * 4 + i;
        if (k < NB) bb[k] = excl;
        excl += v[i];
    }
    __syncthreads();
    for (int k = t; k < NB; k += 256)
        pos[k] = bb[k] + counts[(size_t)b * NB + k];
    if (b == 0) {
        for (int k = t; k < NB; k += 256) bbase[k] = bb[k];
        if (t == 0) bbase[NB] = E;
    }
    __syncthreads();
    int e0 = b * CH;
    int e1 = e0 + CH; if (e1 > E) e1 = E;
    for (int e = e0 + t; e < e1; e += 256) {
        int d = dst[e], s2 = src[e];
        int p = atomicAdd(&pos[d >> 7], 1);
        ebuf[p] = (int)((uint)s2 | ((uint)(d & 127) << 25));
    }
}

// pass E: per-bucket fine CSR
__global__ __launch_bounds__(256) void k_csr(const int* __restrict__ bbase,
                                             const int* __restrict__ ebuf,
                                             int* __restrict__ row_ptr,
                                             int* __restrict__ col,
                                             int N, int E) {
    __shared__ int cnt[128];
    __shared__ int fill[128];
    __shared__ int rowb[128];
    __shared__ int sh[256];
    int t = threadIdx.x, k = blockIdx.x;
    int lo = bbase[k], hi = bbase[k + 1];
    int nlo = k << 7;
    int nn = N - nlo; if (nn > 128) nn = 128;
    if (t < 128) { cnt[t] = 0; fill[t] = 0; }
    __syncthreads();
    for (int i = lo + t; i < hi; i += 256)
        atomicAdd(&cnt[((uint)ebuf[i]) >> 25], 1);
    __syncthreads();
    int v = (t < nn) ? (cnt[t] + 1) : 0;  // +1 self-loop slot
    sh[t] = v;
    __syncthreads();
    int accv = v;
    for (int off = 1; off < 256; off <<= 1) {
        int u = (t >= off) ? sh[t - off] : 0;
        __syncthreads();
        accv += u;
        sh[t] = accv;
        __syncthreads();
    }
    int fbase = lo + nlo;
    if (t < nn) {
        int rb = fbase + accv - v;
        rowb[t] = rb;
        row_ptr[nlo + t] = rb;
        col[rb + cnt[t]] = nlo + t;  // self-loop at end of row
    }
    if (k == 0 && t == 0) row_ptr[N] = E + N;
    __syncthreads();
    for (int i = lo + t; i < hi; i += 256) {
        uint e = (uint)ebuf[i];
        int j = (int)(e >> 25);
        int r = atomicAdd(&fill[j], 1);
        col[rowb[j] + r] = (int)(e & 0x1FFFFFFu);
    }
}

// ---- edge1: wave/node, shfl-free; ONE 128-B line per edge (packed rec1) ----
__global__ __launch_bounds__(256) void k_edge1(const uchar* __restrict__ rec1,
                                               const int* __restrict__ row_ptr,
                                               const int* __restrict__ col,
                                               _Float16* __restrict__ x1pre, int N) {
    int node = blockIdx.x * 4 + (threadIdx.x >> 6);
    if (node >= N) return;
    const int lane = threadIdx.x & 63;
    const int g = lane >> 4;       // edge subgroup 0..3
    const int k4 = lane & 15;      // channel quad (ch 4k4..4k4+3)
    const int hh = k4 >> 1;        // head of those channels
    const uint co = (uint)(k4 * 4);
    const uint ao = 64u + (uint)(hh * 4);
    const float a_dh = *(const float*)(rec1 + (((size_t)node) << 7) + 96 + hh * 4);
    const int s0 = row_ptr[node], s1 = row_ptr[node + 1];
    float den_part = 0.f;
    v2f accL = {0.f, 0.f};
    v2f accH = {0.f, 0.f};
    for (int base = s0; base < s1; base += 64) {
        int cnt = s1 - base; if (cnt > 64) cnt = 64;
        int cntR = (cnt + 3) & ~3;
        int i = 0;
        for (; i + 16 <= cntR; i += 16) {
            int eA = base + i + g, eB = eA + 4, eC = eA + 8, eD = eA + 12;
            int xD = eD < s1 ? eD : s1 - 1;       // only D can run past
            int cA = col[eA], cB = col[eB], cC = col[eC], cD = col[xD];
            const uchar* rA = rec1 + (((uint)cA) << 7);
            const uchar* rB = rec1 + (((uint)cB) << 7);
            const uchar* rC = rec1 + (((uint)cC) << 7);
            const uchar* rD = rec1 + (((uint)cD) << 7);
            uint hA = *(const uint*)(rA + co);
            uint hB = *(const uint*)(rB + co);
            uint hC = *(const uint*)(rC + co);
            uint hD = *(const uint*)(rD + co);
            float lA = *(const float*)(rA + ao) + a_dh;
            float lB = *(const float*)(rB + ao) + a_dh;
            float lC = *(const float*)(rC + ao) + a_dh;
            float lD = *(const float*)(rD + ao) + a_dh;
            lA = lA > 0.f ? lA : 0.2f * lA;
            lB = lB > 0.f ? lB : 0.2f * lB;
            lC = lC > 0.f ? lC : 0.2f * lC;
            lD = lD > 0.f ? lD : 0.2f * lD;
            float wA = __expf(lA);
            float wB = __expf(lB);
            float wC = __expf(lC);
            float wD = (eD < s1) ? __expf(lD) : 0.f;
            den_part += wA + wB + wC + wD;
            v2f wA2 = {wA, wA}, wB2 = {wB, wB}, wC2 = {wC, wC}, wD2 = {wD, wD};
            accL += wA2 * fp8x2f<false>(hA);
            accH += wA2 * fp8x2f<true>(hA);
            accL += wB2 * fp8x2f<false>(hB);
            accH += wB2 * fp8x2f<true>(hB);
            accL += wC2 * fp8x2f<false>(hC);
            accH += wC2 * fp8x2f<true>(hC);
            accL += wD2 * fp8x2f<false>(hD);
            accH += wD2 * fp8x2f<true>(hD);
        }
        int rem = cntR - i;
        if (rem & 8) {  // 8 edges
            int eA = base + i + g, eB = eA + 4;
            int xB = eB < s1 ? eB : s1 - 1;
            int cA = col[eA], cB = col[xB];
            const uchar* rA = rec1 + (((uint)cA) << 7);
            const uchar* rB = rec1 + (((uint)cB) << 7);
            uint hA = *(const uint*)(rA + co);
            uint hB = *(const uint*)(rB + co);
            float lA = *(const float*)(rA + ao) + a_dh;
            float lB = *(const float*)(rB + ao) + a_dh;
            lA = lA > 0.f ? lA : 0.2f * lA;
            lB = lB > 0.f ? lB : 0.2f * lB;
            float wA = __expf(lA);
            float wB = (eB < s1) ? __expf(lB) : 0.f;
            den_part += wA + wB;
            v2f wA2 = {wA, wA}, wB2 = {wB, wB};
            accL += wA2 * fp8x2f<false>(hA);
            accH += wA2 * fp8x2f<true>(hA);
            accL += wB2 * fp8x2f<false>(hB);
            accH += wB2 * fp8x2f<true>(hB);
            i += 8;
        }
        if (rem & 4) {  // 4 edges
            int eA = base + i + g;
            int xA = eA < s1 ? eA : s1 - 1;
            int cA = col[xA];
            const uchar* rA = rec1 + (((uint)cA) << 7);
            uint hA = *(const uint*)(rA + co);
            float lA = *(const float*)(rA + ao) + a_dh;
            lA = lA > 0.f ? lA : 0.2f * lA;
            float wA = (eA < s1) ? __expf(lA) : 0.f;
            den_part += wA;
            v2f wA2 = {wA, wA};
            accL += wA2 * fp8x2f<false>(hA);
            accH += wA2 * fp8x2f<true>(hA);
        }
    }
    float a0 = accL.x, a1 = accL.y, a2 = accH.x, a3 = accH.y;
    a0 += __shfl_xor(a0, 16); a0 += __shfl_xor(a0, 32);
    a1 += __shfl_xor(a1, 16); a1 += __shfl_xor(a1, 32);
    a2 += __shfl_xor(a2, 16); a2 += __shfl_xor(a2, 32);
    a3 += __shfl_xor(a3, 16); a3 += __shfl_xor(a3, 32);
    den_part += __shfl_xor(den_part, 16);
    den_part += __shfl_xor(den_part, 32);   // per-lane den for head hh
    if (lane < 16) {
        float invd = 1.f / (den_part * S1);
        h4v o;
        o[0] = (_Float16)(a0 * invd);
        o[1] = (_Float16)(a1 * invd);
        o[2] = (_Float16)(a2 * invd);
        o[3] = (_Float16)(a3 * invd);
        *(h4v*)(x1pre + (size_t)node * 64 + co) = o;
    }
}

// ---- edge2: wave/node, shfl-free; fp8 table gathers, writes x2 fp16 ----
__global__ __launch_bounds__(256) void k_edge2(const uchar* __restrict__ h2f8,
                                               const float* __restrict__ al2s,
                                               const float* __restrict__ al2d,
                                               const int* __restrict__ row_ptr,
                                               const int* __restrict__ col,
                                               _Float16* __restrict__ x2, int N) {
    int node = blockIdx.x * 4 + (threadIdx.x >> 6);
    if (node >= N) return;
    const int lane = threadIdx.x & 63;
    const int g = lane >> 4;    // edge group 0..3
    const int k8 = lane & 15;   // channel oct (ch 8k8..8k8+7 of 128)
    const uint co = (uint)(k8 * 8);
    const float a_d = al2d[node];
    const int s0 = row_ptr[node], s1 = row_ptr[node + 1];
    v2f acc0 = {0.f, 0.f}, acc1 = {0.f, 0.f}, acc2 = {0.f, 0.f}, acc3 = {0.f, 0.f};
    float den_part = 0.f;
    for (int base = s0; base < s1; base += 64) {
        int cnt = s1 - base; if (cnt > 64) cnt = 64;
        int cntR = (cnt + 3) & ~3;
        int i = 0;
        for (; i + 16 <= cntR; i += 16) {
            int eA = base + i + g, eB = eA + 4, eC = eA + 8, eD = eA + 12;
            int xD = eD < s1 ? eD : s1 - 1;
            int cA = col[eA], cB = col[eB], cC = col[eC], cD = col[xD];
            uint2 hA = *(const uint2*)(h2f8 + ((((uint)cA) << 7) | co));
            uint2 hB = *(const uint2*)(h2f8 + ((((uint)cB) << 7) | co));
            uint2 hC = *(const uint2*)(h2f8 + ((((uint)cC) << 7) | co));
            uint2 hD = *(const uint2*)(h2f8 + ((((uint)cD) << 7) | co));
            float lA = al2s[(uint)cA] + a_d;
            float lB = al2s[(uint)cB] + a_d;
            float lC = al2s[(uint)cC] + a_d;
            float lD = al2s[(uint)cD] + a_d;
            lA = lA > 0.f ? lA : 0.2f * lA;
            lB = lB > 0.f ? lB : 0.2f * lB;
            lC = lC > 0.f ? lC : 0.2f * lC;
            lD = lD > 0.f ? lD : 0.2f * lD;
            float wA = __expf(lA);
            float wB = __expf(lB);
            float wC = __expf(lC);
            float wD = (eD < s1) ? __expf(lD) : 0.f;
            den_part += wA + wB + wC + wD;
            v2f wA2 = {wA, wA}, wB2 = {wB, wB}, wC2 = {wC, wC}, wD2 = {wD, wD};
            acc0 += wA2 * fp8x2f<false>(hA.x);
            acc1 += wA2 * fp8x2f<true>(hA.x);
            acc2 += wA2 * fp8x2f<false>(hA.y);
            acc3 += wA2 * fp8x2f<true>(hA.y);
            acc0 += wB2 * fp8x2f<false>(hB.x);
            acc1 += wB2 * fp8x2f<true>(hB.x);
            acc2 += wB2 * fp8x2f<false>(hB.y);
            acc3 += wB2 * fp8x2f<true>(hB.y);
            acc0 += wC2 * fp8x2f<false>(hC.x);
            acc1 += wC2 * fp8x2f<true>(hC.x);
            acc2 += wC2 * fp8x2f<false>(hC.y);
            acc3 += wC2 * fp8x2f<true>(hC.y);
            acc0 += wD2 * fp8x2f<false>(hD.x);
            acc1 += wD2 * fp8x2f<true>(hD.x);
            acc2 += wD2 * fp8x2f<false>(hD.y);
            acc3 += wD2 * fp8x2f<true>(hD.y);
        }
        int rem = cntR - i;
        if (rem & 8) {
            int eA = base + i + g, eB = eA + 4;
            int xB = eB < s1 ? eB : s1 - 1;
            int cA = col[eA], cB = col[xB];
            uint2 hA = *(const uint2*)(h2f8 + ((((uint)cA) << 7) | co));
            uint2 hB = *(const uint2*)(h2f8 + ((((uint)cB) << 7) | co));
            float lA = al2s[(uint)cA] + a_d;
            float lB = al2s[(uint)cB] + a_d;
            lA = lA > 0.f ? lA : 0.2f * lA;
            lB = lB > 0.f ? lB : 0.2f * lB;
            float wA = __expf(lA);
            float wB = (eB < s1) ? __expf(lB) : 0.f;
            den_part += wA + wB;
            v2f wA2 = {wA, wA}, wB2 = {wB, wB};
            acc0 += wA2 * fp8x2f<false>(hA.x);
            acc1 += wA2 * fp8x2f<true>(hA.x);
            acc2 += wA2 * fp8x2f<false>(hA.y);
            acc3 += wA2 * fp8x2f<true>(hA.y);
            acc0 += wB2 * fp8x2f<false>(hB.x);
            acc1 += wB2 * fp8x2f<true>(hB.x);
            acc2 += wB2 * fp8x2f<false>(hB.y);
            acc3 += wB2 * fp8x2f<true>(hB.y);
            i += 8;
        }
        if (rem & 4) {
            int eA = base + i + g;
            int xA = eA < s1 ? eA : s1 - 1;
            int cA = col[xA];
            uint2 hA = *(const uint2*)(h2f8 + ((((uint)cA) << 7) | co));
            float lA = al2s[(uint)cA] + a_d;
            lA = lA > 0.f ? lA : 0.2f * lA;
            float wA = (eA < s1) ? __expf(lA) : 0.f;
            den_part += wA;
            v2f wA2 = {wA, wA};
            acc0 += wA2 * fp8x2f<false>(hA.x);
            acc1 += wA2 * fp8x2f<true>(hA.x);
            acc2 += wA2 * fp8x2f<false>(hA.y);
            acc3 += wA2 * fp8x2f<true>(hA.y);
        }
    }
    den_part += __shfl_xor(den_part, 16);
    den_part += __shfl_xor(den_part, 32);
    float r0 = acc0.x, r1 = acc0.y, r2 = acc1.x, r3 = acc1.y;
    float r4 = acc2.x, r5 = acc2.y, r6 = acc3.x, r7 = acc3.y;
    r0 += __shfl_xor(r0, 16); r0 += __shfl_xor(r0, 32);
    r1 += __shfl_xor(r1, 16); r1 += __shfl_xor(r1, 32);
    r2 += __shfl_xor(r2, 16); r2 += __shfl_xor(r2, 32);
    r3 += __shfl_xor(r3, 16); r3 += __shfl_xor(r3, 32);
    r4 += __shfl_xor(r4, 16); r4 += __shfl_xor(r4, 32);
    r5 += __shfl_xor(r5, 16); r5 += __shfl_xor(r5, 32);
    r6 += __shfl_xor(r6, 16); r6 += __shfl_xor(r6, 32);
    r7 += __shfl_xor(r7, 16); r7 += __shfl_xor(r7, 32);
    if (lane < 16) {
        float invd = 1.f / (den_part * S2);
        h8v o;
        o[0] = (_Float16)(r0 * invd);
        o[1] = (_Float16)(r1 * invd);
        o[2] = (_Float16)(r2 * invd);
        o[3] = (_Float16)(r3 * invd);
        o[4] = (_Float16)(r4 * invd);
        o[5] = (_Float16)(r5 * invd);
        o[6] = (_Float16)(r6 * invd);
        o[7] = (_Float16)(r7 * invd);
        *(h8v*)(x2 + (size_t)node * 128 + co) = o;
    }
}

// ---- k_poolfc: one block per graph; batch sorted -> binary-search node range,
// mean-pool in registers (no atomics, no memset), then wave 0 does FC+logsoftmax.
__global__ __launch_bounds__(128) void k_poolfc(const _Float16* __restrict__ x2,
                                                const int* __restrict__ batch,
                                                const float* __restrict__ b2,
                                                const float* __restrict__ fcw,
                                                const float* __restrict__ fcb,
                                                float* __restrict__ out,
                                                int N, int G) {
    __shared__ float sp[128];
    const int g = blockIdx.x;
    const int t = threadIdx.x;
    int lo = 0, hi = N;
    while (lo < hi) { int m = (lo + hi) >> 1; if (batch[m] < g) lo = m + 1; else hi = m; }
    const int s = lo;
    hi = N;
    while (lo < hi) { int m = (lo + hi) >> 1; if (batch[m] < g + 1) lo = m + 1; else hi = m; }
    const int e = lo;
    float a0 = 0.f, a1 = 0.f, a2 = 0.f, a3 = 0.f;
    int n = s;
    for (; n + 4 <= e; n += 4) {
        a0 += (float)x2[(size_t)(n + 0) * 128 + t];
        a1 += (float)x2[(size_t)(n + 1) * 128 + t];
        a2 += (float)x2[(size_t)(n + 2) * 128 + t];
        a3 += (float)x2[(size_t)(n + 3) * 128 + t];
    }
    for (; n < e; ++n) a0 += (float)x2[(size_t)n * 128 + t];
    float inv = 1.f / fmaxf((float)(e - s), 1.f);
    sp[t] = (a0 + a1 + a2 + a3) * inv + b2[t];
    __syncthreads();
    if (t < 64) {
        int c = t;
        float2 p = ((const float2*)sp)[c];
        float l[10];
#pragma unroll
        for (int j = 0; j < 10; ++j)
            l[j] = p.x * fcw[(2 * c) * 10 + j] + p.y * fcw[(2 * c + 1) * 10 + j];
#pragma unroll
        for (int j = 0; j < 10; ++j)
            for (int off = 1; off < 64; off <<= 1) l[j] += __shfl_xor(l[j], off);
        if (c == 0) {
            float lj[10];
            float m = -1e30f;
#pragma unroll
            for (int j = 0; j < 10; ++j) {
                lj[j] = l[j] + fcb[j];
                m = fmaxf(m, lj[j]);
            }
            float sde = 0.f;
#pragma unroll
            for (int j = 0; j < 10; ++j) sde += expf(lj[j] - m);
            float ls = logf(sde);
#pragma unroll
            for (int j = 0; j < 10; ++j) out[(size_t)g * 10 + j] = lj[j] - m - ls;
        }
    }
}

extern "C" void kernel_launch(void* const* d_in, const int* in_sizes, int n_in,
                              void* d_out, int out_size, void* d_ws, size_t ws_size,
                              hipStream_t stream) {
    const float* x     = (const float*)d_in[0];
    const int*   ei    = (const int*)d_in[1];
    const int*   batch = (const int*)d_in[2];
    const float* W1    = (const float*)d_in[3];
    const float* as1   = (const float*)d_in[4];
    const float* ad1   = (const float*)d_in[5];
    const float* b1    = (const float*)d_in[6];
    const float* W2    = (const float*)d_in[7];
    const float* as2   = (const float*)d_in[8];
    const float* ad2   = (const float*)d_in[9];
    const float* b2    = (const float*)d_in[10];
    const float* fcw   = (const float*)d_in[11];
    const float* fcb   = (const float*)d_in[12];
    float* out = (float*)d_out;

    const int N = in_sizes[0] / 128;
    const int E = in_sizes[1] / 2;
    const int G = out_size / 10;
    const int* srcp = ei;
    const int* dstp = ei + E;

    // workspace (float units):
    //   [0,32N)     rec1 (N x 128B packed) -- dead after k_edge1
    //   [32N,64N)   x1pre (fp16 N*64)      -- dead after k_gemm2
    //   [0,64N)     x2 (fp16 N*128) -- aliases dead rec1/x1pre
    //   [128N,160N) h2f8 (N*128 fp8)
    //   [192N,193N) al2s  [193N,194N) al2d
    //   [194N,...)  int region (ebuf, counts, btot, bbase, row_ptr, col)
    float* wf = (float*)d_ws;
    uchar*    rec1  = (uchar*)wf;
    _Float16* x1pre = (_Float16*)(wf + (size_t)N * 32);
    _Float16* x2    = (_Float16*)wf;
    uchar*    h2f8  = (uchar*)(wf + (size_t)N * 128);
    float* al2s_  = wf + (size_t)N * 192;
    float* al2d_  = wf + (size_t)N * 193;

    const int NB = (N + 127) >> 7;      // 782 buckets (requires NB <= 784)
    const int C  = 256;                 // histogram/scatter blocks (longer runs)
    const int CH = (E + C - 1) / C;     // edges per block

    int* ib = (int*)(((uintptr_t)(wf + (size_t)N * 194) + 15) & ~(uintptr_t)15);
    int* ebuf    = ib;                              // [E] packed src|((dst&127)<<25)
    int* counts  = ib + (size_t)E;                  // [C*NB]
    int* btot    = counts + (size_t)C * NB;         // [NB]
    int* bbase   = btot + NB;                       // [NB+1]
    int* row_ptr = bbase + NB + 1;                  // [N+1]
    int* col     = row_ptr + N + 1;                 // [E+N]

    const int nb64 = (N + 63) / 64;
    const int nb4  = (N + 3) / 4;

    k_g1h<<<nb64 + C, 256, 0, stream>>>(x, W1, as1, ad1, rec1, dstp, counts,
                                        N, E, CH, NB, nb64);
    k_bscan<<<NB, 256, 0, stream>>>(counts, btot, C, NB);
    k_bucket<<<C, 256, 0, stream>>>(srcp, dstp, counts, btot, bbase, ebuf, E, CH, NB);
    k_csr<<<NB, 256, 0, stream>>>(bbase, ebuf, row_ptr, col, N, E);
    k_edge1<<<nb4, 256, 0, stream>>>(rec1, row_ptr, col, x1pre, N);
    k_gemm2<<<nb64, 256, 0, stream>>>(x1pre, W2, b1, as2, ad2, h2f8, al2s_, al2d_, N);
    k_edge2<<<nb4, 256, 0, stream>>>(h2f8, al2s_, al2d_, row_ptr, col, x2, N);
    k_poolfc<<<G, 128, 0, stream>>>(x2, batch, b2, fcw, fcb, out, N, G);
}

// Round 12
// 322.744 us; speedup vs baseline: 1.0808x; 1.0162x over previous
//
#include <hip/hip_runtime.h>
#include <math.h>

typedef unsigned int uint;
typedef unsigned short ushort;
typedef unsigned char uchar;
typedef __attribute__((ext_vector_type(2))) float v2f;
typedef __attribute__((ext_vector_type(4))) _Float16 h4v;   // 8 B
typedef __attribute__((ext_vector_type(8))) _Float16 h8v;   // 16 B

#define S1 4.0f
#define S2 16.0f

template <bool HI>
__device__ inline v2f fp8x2f(uint u) {
    return __builtin_amdgcn_cvt_pk_f32_fp8((int)u, HI);
}

template <int PAT>
__device__ inline float swz(float v) {
    return __int_as_float(__builtin_amdgcn_ds_swizzle(__float_as_int(v), PAT));
}

// ---- k_g1h: GEMM1 + edge histogram fused as independent block ranges ----
// blocks [0,GB): rec1[N] packed 128-B record {64B h1 fp8, 32B al1s, 32B al1d}
//                = x[N,128] @ W1[128,64]
// blocks [GB,GB+C): per-block LDS histogram of dst>>7 into counts
__global__ __launch_bounds__(256) void k_g1h(const float* __restrict__ x,
                                             const float* __restrict__ W1,
                                             const float* __restrict__ as1,
                                             const float* __restrict__ ad1,
                                             uchar* __restrict__ rec1,
                                             const int* __restrict__ dst,
                                             int* __restrict__ counts,
                                             int N, int E, int CH, int NB, int GB) {
    __shared__ float sB[128 * 64];
    __shared__ float sA[64 * 68];
    const int t = threadIdx.x;
    if (blockIdx.x >= GB) {
        // ---- histogram part ----
        int b = blockIdx.x - GB;
        int* hist = (int*)sB;
        for (int k = t; k < NB; k += 256) hist[k] = 0;
        __syncthreads();
        int e0 = b * CH;
        int e1 = e0 + CH; if (e1 > E) e1 = E;
        for (int e = e0 + t; e < e1; e += 256)
            atomicAdd(&hist[dst[e] >> 7], 1);
        __syncthreads();
        for (int k = t; k < NB; k += 256) counts[(size_t)b * NB + k] = hist[k];
        return;
    }
    // ---- gemm1 part ----
    const int n0 = blockIdx.x * 64;
    {
        const float4* w4 = (const float4*)W1;
        float4* s4 = (float4*)sB;
#pragma unroll
        for (int i = 0; i < 8; ++i) s4[t + i * 256] = w4[t + i * 256];
    }
    const int r0 = (t >> 3) * 2;
    const int c0 = (t & 7) * 8;   // head = t&7, channels c0..c0+7
    float acc0[8] = {0, 0, 0, 0, 0, 0, 0, 0};
    float acc1[8] = {0, 0, 0, 0, 0, 0, 0, 0};
    for (int kb = 0; kb < 2; ++kb) {
        __syncthreads();
#pragma unroll
        for (int i = 0; i < 4; ++i) {
            int idx = t + i * 256;
            int r = idx >> 4, kc = idx & 15;
            int n = n0 + r;
            float4 v = make_float4(0.f, 0.f, 0.f, 0.f);
            if (n < N) v = ((const float4*)x)[(size_t)n * 32 + kb * 16 + kc];
            *(float4*)&sA[r * 68 + kc * 4] = v;
        }
        __syncthreads();
        const float* bptr = &sB[kb * 64 * 64];
#pragma unroll 8
        for (int kk = 0; kk < 64; ++kk) {
            float a0 = sA[r0 * 68 + kk];
            float a1 = sA[(r0 + 1) * 68 + kk];
            const float* bp = &bptr[kk * 64 + c0];
            float4 b0 = *(const float4*)bp;
            float4 b1v = *(const float4*)(bp + 4);
            acc0[0] += a0 * b0.x; acc0[1] += a0 * b0.y; acc0[2] += a0 * b0.z; acc0[3] += a0 * b0.w;
            acc0[4] += a0 * b1v.x; acc0[5] += a0 * b1v.y; acc0[6] += a0 * b1v.z; acc0[7] += a0 * b1v.w;
            acc1[0] += a1 * b0.x; acc1[1] += a1 * b0.y; acc1[2] += a1 * b0.z; acc1[3] += a1 * b0.w;
            acc1[4] += a1 * b1v.x; acc1[5] += a1 * b1v.y; acc1[6] += a1 * b1v.z; acc1[7] += a1 * b1v.w;
        }
    }
    float ps0 = 0.f, pd0 = 0.f, ps1 = 0.f, pd1 = 0.f;
#pragma unroll
    for (int i = 0; i < 8; ++i) {
        float ws = as1[c0 + i], wd = ad1[c0 + i];
        ps0 += acc0[i] * ws; pd0 += acc0[i] * wd;
        ps1 += acc1[i] * ws; pd1 += acc1[i] * wd;
    }
    int n = n0 + r0;
    int head = t & 7;
    if (n < N) {
        int q0 = 0, q1 = 0;
        q0 = __builtin_amdgcn_cvt_pk_fp8_f32(acc0[0] * S1, acc0[1] * S1, q0, false);
        q0 = __builtin_amdgcn_cvt_pk_fp8_f32(acc0[2] * S1, acc0[3] * S1, q0, true);
        q1 = __builtin_amdgcn_cvt_pk_fp8_f32(acc0[4] * S1, acc0[5] * S1, q1, false);
        q1 = __builtin_amdgcn_cvt_pk_fp8_f32(acc0[6] * S1, acc0[7] * S1, q1, true);
        uint2 p; p.x = (uint)q0; p.y = (uint)q1;
        uchar* rp = rec1 + (size_t)n * 128;
        *(uint2*)(rp + c0) = p;
        *(float*)(rp + 64 + head * 4) = ps0;
        *(float*)(rp + 96 + head * 4) = pd0;
    }
    if (n + 1 < N) {
        int q0 = 0, q1 = 0;
        q0 = __builtin_amdgcn_cvt_pk_fp8_f32(acc1[0] * S1, acc1[1] * S1, q0, false);
        q0 = __builtin_amdgcn_cvt_pk_fp8_f32(acc1[2] * S1, acc1[3] * S1, q0, true);
        q1 = __builtin_amdgcn_cvt_pk_fp8_f32(acc1[4] * S1, acc1[5] * S1, q1, false);
        q1 = __builtin_amdgcn_cvt_pk_fp8_f32(acc1[6] * S1, acc1[7] * S1, q1, true);
        uint2 p; p.x = (uint)q0; p.y = (uint)q1;
        uchar* rp = rec1 + (size_t)(n + 1) * 128;
        *(uint2*)(rp + c0) = p;
        *(float*)(rp + 64 + head * 4) = ps1;
        *(float*)(rp + 96 + head * 4) = pd1;
    }
}

// ---- GEMM2: h2f8[N,128](fp8,S2) = relu(x1pre(fp16)+b1) @ W2[64,128], fused al2 ----
__global__ __launch_bounds__(256) void k_gemm2(const _Float16* __restrict__ x1pre,
                                               const float* __restrict__ W2,
                                               const float* __restrict__ b1,
                                               const float* __restrict__ as2,
                                               const float* __restrict__ ad2,
                                               uchar* __restrict__ h2f8,
                                               float* __restrict__ al2s,
                                               float* __restrict__ al2d, int N) {
    __shared__ float sB[64 * 128];
    __shared__ float sA[64 * 68];
    const int t = threadIdx.x;
    const int n0 = blockIdx.x * 64;
    {
        const float4* w4 = (const float4*)W2;
        float4* s4 = (float4*)sB;
#pragma unroll
        for (int i = 0; i < 8; ++i) s4[t + i * 256] = w4[t + i * 256];
    }
#pragma unroll
    for (int i = 0; i < 4; ++i) {
        int idx = t + i * 256;
        int r = idx >> 4, kc = idx & 15;
        int n = n0 + r;
        float4 v = make_float4(0.f, 0.f, 0.f, 0.f);
        if (n < N) {
            h4v hv = *(const h4v*)(x1pre + (size_t)n * 64 + kc * 4);
            float4 bb = ((const float4*)b1)[kc];
            v.x = fmaxf((float)hv[0] + bb.x, 0.f);
            v.y = fmaxf((float)hv[1] + bb.y, 0.f);
            v.z = fmaxf((float)hv[2] + bb.z, 0.f);
            v.w = fmaxf((float)hv[3] + bb.w, 0.f);
        }
        *(float4*)&sA[r * 68 + kc * 4] = v;
    }
    __syncthreads();
    const int r0 = (t >> 3) * 2;
    const int cb = (t & 7) * 4;
    float acc0[16], acc1[16];
#pragma unroll
    for (int i = 0; i < 16; ++i) { acc0[i] = 0.f; acc1[i] = 0.f; }
#pragma unroll 4
    for (int k = 0; k < 64; ++k) {
        float a0 = sA[r0 * 68 + k];
        float a1 = sA[(r0 + 1) * 68 + k];
#pragma unroll
        for (int j = 0; j < 4; ++j) {
            float4 b = *(const float4*)&sB[k * 128 + cb + 32 * j];
            acc0[j * 4 + 0] += a0 * b.x; acc0[j * 4 + 1] += a0 * b.y;
            acc0[j * 4 + 2] += a0 * b.z; acc0[j * 4 + 3] += a0 * b.w;
            acc1[j * 4 + 0] += a1 * b.x; acc1[j * 4 + 1] += a1 * b.y;
            acc1[j * 4 + 2] += a1 * b.z; acc1[j * 4 + 3] += a1 * b.w;
        }
    }
    float ps0 = 0.f, pd0 = 0.f, ps1 = 0.f, pd1 = 0.f;
#pragma unroll
    for (int j = 0; j < 4; ++j)
#pragma unroll
        for (int i = 0; i < 4; ++i) {
            int cc = cb + 32 * j + i;
            float ws = as2[cc], wd = ad2[cc];
            ps0 += acc0[j * 4 + i] * ws; pd0 += acc0[j * 4 + i] * wd;
            ps1 += acc1[j * 4 + i] * ws; pd1 += acc1[j * 4 + i] * wd;
        }
#pragma unroll
    for (int off = 1; off < 8; off <<= 1) {
        ps0 += __shfl_xor(ps0, off); pd0 += __shfl_xor(pd0, off);
        ps1 += __shfl_xor(ps1, off); pd1 += __shfl_xor(pd1, off);
    }
    int n = n0 + r0;
    if (n < N) {
#pragma unroll
        for (int j = 0; j < 4; ++j) {
            int q = 0;
            q = __builtin_amdgcn_cvt_pk_fp8_f32(acc0[j * 4 + 0] * S2, acc0[j * 4 + 1] * S2, q, false);
            q = __builtin_amdgcn_cvt_pk_fp8_f32(acc0[j * 4 + 2] * S2, acc0[j * 4 + 3] * S2, q, true);
            *(uint*)&h2f8[(size_t)n * 128 + cb + 32 * j] = (uint)q;
        }
        if ((t & 7) == 0) { al2s[n] = ps0; al2d[n] = pd0; }
    }
    if (n + 1 < N) {
#pragma unroll
        for (int j = 0; j < 4; ++j) {
            int q = 0;
            q = __builtin_amdgcn_cvt_pk_fp8_f32(acc1[j * 4 + 0] * S2, acc1[j * 4 + 1] * S2, q, false);
            q = __builtin_amdgcn_cvt_pk_fp8_f32(acc1[j * 4 + 2] * S2, acc1[j * 4 + 3] * S2, q, true);
            *(uint*)&h2f8[(size_t)(n + 1) * 128 + cb + 32 * j] = (uint)q;
        }
        if ((t & 7) == 0) { al2s[n + 1] = ps1; al2d[n + 1] = pd1; }
    }
}

// ========== atomic-free CSR build (separate dispatches) ====

// pass B: per-bucket exclusive scan over blocks (one block per bucket)
__global__ __launch_bounds__(256) void k_bscan(int* __restrict__ counts,
                                               int* __restrict__ btot,
                                               int C, int NB) {
    __shared__ int sh[256];
    int t = threadIdx.x, k = blockIdx.x;
    int v[4];
#pragma unroll
    for (int i = 0; i < 4; ++i) {
        int b = t * 4 + i;
        v[i] = (b < C) ? counts[(size_t)b * NB + k] : 0;
    }
    int s = v[0] + v[1] + v[2] + v[3];
    sh[t] = s;
    __syncthreads();
    int accv = s;
    for (int off = 1; off < 256; off <<= 1) {
        int u = (t >= off) ? sh[t - off] : 0;
        __syncthreads();
        accv += u;
        sh[t] = accv;
        __syncthreads();
    }
    int excl = accv - s;
#pragma unroll
    for (int i = 0; i < 4; ++i) {
        int b = t * 4 + i;
        if (b < C) counts[(size_t)b * NB + k] = excl;
        excl += v[i];
    }
    if (t == 255) btot[k] = accv;
}

// pass D: scatter edges into bucket-sorted ebuf; bbase scan folded in
__global__ __launch_bounds__(256) void k_bucket(const int* __restrict__ src,
                                                const int* __restrict__ dst,
                                                const int* __restrict__ counts,
                                                const int* __restrict__ btot,
                                                int* __restrict__ bbase,
                                                int* __restrict__ ebuf,
                                                int E, int CH, int NB) {
    __shared__ int pos[784];
    __shared__ int sh[256];
    __shared__ int bb[784];
    int t = threadIdx.x, b = blockIdx.x;
    int v[4];
#pragma unroll
    for (int i = 0; i < 4; ++i) {
        int k = t * 4 + i;
        v[i] = (k < NB) ? btot[k] : 0;
    }
    int s = v[0] + v[1] + v[2] + v[3];
    sh[t] = s;
    __syncthreads();
    int accv = s;
    for (int off = 1; off < 256; off <<= 1) {
        int u = (t >= off) ? sh[t - off] : 0;
        __syncthreads();
        accv += u;
        sh[t] = accv;
        __syncthreads();
    }
    int excl = accv - s;
#pragma unroll
    for (int i = 0; i < 4; ++i) {
        int k = t * 4 + i;
        if (k < NB) bb[k] = excl;
        excl += v[i];
    }
    __syncthreads();
    for (int k = t; k < NB; k += 256)
        pos[k] = bb[k] + counts[(size_t)b * NB + k];
    if (b == 0) {
        for (int k = t; k < NB; k += 256) bbase[k] = bb[k];
        if (t == 0) bbase[NB] = E;
    }
    __syncthreads();
    int e0 = b * CH;
    int e1 = e0 + CH; if (e1 > E) e1 = E;
    for (int e = e0 + t; e < e1; e += 256) {
        int d = dst[e], s2 = src[e];
        int p = atomicAdd(&pos[d >> 7], 1);
        ebuf[p] = (int)((uint)s2 | ((uint)(d & 127) << 25));
    }
}

// pass E: per-bucket fine CSR
__global__ __launch_bounds__(256) void k_csr(const int* __restrict__ bbase,
                                             const int* __restrict__ ebuf,
                                             int* __restrict__ row_ptr,
                                             int* __restrict__ col,
                                             int N, int E) {
    __shared__ int cnt[128];
    __shared__ int fill[128];
    __shared__ int rowb[128];
    __shared__ int sh[256];
    int t = threadIdx.x, k = blockIdx.x;
    int lo = bbase[k], hi = bbase[k + 1];
    int nlo = k << 7;
    int nn = N - nlo; if (nn > 128) nn = 128;
    if (t < 128) { cnt[t] = 0; fill[t] = 0; }
    __syncthreads();
    for (int i = lo + t; i < hi; i += 256)
        atomicAdd(&cnt[((uint)ebuf[i]) >> 25], 1);
    __syncthreads();
    int v = (t < nn) ? (cnt[t] + 1) : 0;  // +1 self-loop slot
    sh[t] = v;
    __syncthreads();
    int accv = v;
    for (int off = 1; off < 256; off <<= 1) {
        int u = (t >= off) ? sh[t - off] : 0;
        __syncthreads();
        accv += u;
        sh[t] = accv;
        __syncthreads();
    }
    int fbase = lo + nlo;
    if (t < nn) {
        int rb = fbase + accv - v;
        rowb[t] = rb;
        row_ptr[nlo + t] = rb;
        col[rb + cnt[t]] = nlo + t;  // self-loop at end of row
    }
    if (k == 0 && t == 0) row_ptr[N] = E + N;
    __syncthreads();
    for (int i = lo + t; i < hi; i += 256) {
        uint e = (uint)ebuf[i];
        int j = (int)(e >> 25);
        int r = atomicAdd(&fill[j], 1);
        col[rowb[j] + r] = (int)(e & 0x1FFFFFFu);
    }
}

// ---- edge1: wave/node, shfl-free; ONE 128-B line per edge (packed rec1) ----
__global__ __launch_bounds__(256) void k_edge1(const uchar* __restrict__ rec1,
                                               const int* __restrict__ row_ptr,
                                               const int* __restrict__ col,
                                               _Float16* __restrict__ x1pre, int N) {
    int node = blockIdx.x * 4 + (threadIdx.x >> 6);
    if (node >= N) return;
    const int lane = threadIdx.x & 63;
    const int g = lane >> 4;       // edge subgroup 0..3
    const int k4 = lane & 15;      // channel quad (ch 4k4..4k4+3)
    const int hh = k4 >> 1;        // head of those channels
    const uint co = (uint)(k4 * 4);
    const uint ao = 64u + (uint)(hh * 4);
    const float a_dh = *(const float*)(rec1 + (((size_t)node) << 7) + 96 + hh * 4);
    const int s0 = row_ptr[node], s1 = row_ptr[node + 1];
    float den_part = 0.f;
    v2f accL = {0.f, 0.f};
    v2f accH = {0.f, 0.f};
    for (int base = s0; base < s1; base += 64) {
        int cnt = s1 - base; if (cnt > 64) cnt = 64;
        int cntR = (cnt + 3) & ~3;
        int i = 0;
        for (; i + 16 <= cntR; i += 16) {
            int eA = base + i + g, eB = eA + 4, eC = eA + 8, eD = eA + 12;
            int xD = eD < s1 ? eD : s1 - 1;       // only D can run past
            int cA = col[eA], cB = col[eB], cC = col[eC], cD = col[xD];
            const uchar* rA = rec1 + (((uint)cA) << 7);
            const uchar* rB = rec1 + (((uint)cB) << 7);
            const uchar* rC = rec1 + (((uint)cC) << 7);
            const uchar* rD = rec1 + (((uint)cD) << 7);
            uint hA = *(const uint*)(rA + co);
            uint hB = *(const uint*)(rB + co);
            uint hC = *(const uint*)(rC + co);
            uint hD = *(const uint*)(rD + co);
            float lA = *(const float*)(rA + ao) + a_dh;
            float lB = *(const float*)(rB + ao) + a_dh;
            float lC = *(const float*)(rC + ao) + a_dh;
            float lD = *(const float*)(rD + ao) + a_dh;
            lA = lA > 0.f ? lA : 0.2f * lA;
            lB = lB > 0.f ? lB : 0.2f * lB;
            lC = lC > 0.f ? lC : 0.2f * lC;
            lD = lD > 0.f ? lD : 0.2f * lD;
            float wA = __expf(lA);
            float wB = __expf(lB);
            float wC = __expf(lC);
            float wD = (eD < s1) ? __expf(lD) : 0.f;
            den_part += wA + wB + wC + wD;
            v2f wA2 = {wA, wA}, wB2 = {wB, wB}, wC2 = {wC, wC}, wD2 = {wD, wD};
            accL += wA2 * fp8x2f<false>(hA);
            accH += wA2 * fp8x2f<true>(hA);
            accL += wB2 * fp8x2f<false>(hB);
            accH += wB2 * fp8x2f<true>(hB);
            accL += wC2 * fp8x2f<false>(hC);
            accH += wC2 * fp8x2f<true>(hC);
            accL += wD2 * fp8x2f<false>(hD);
            accH += wD2 * fp8x2f<true>(hD);
        }
        int rem = cntR - i;
        if (rem & 8) {  // 8 edges
            int eA = base + i + g, eB = eA + 4;
            int xB = eB < s1 ? eB : s1 - 1;
            int cA = col[eA], cB = col[xB];
            const uchar* rA = rec1 + (((uint)cA) << 7);
            const uchar* rB = rec1 + (((uint)cB) << 7);
            uint hA = *(const uint*)(rA + co);
            uint hB = *(const uint*)(rB + co);
            float lA = *(const float*)(rA + ao) + a_dh;
            float lB = *(const float*)(rB + ao) + a_dh;
            lA = lA > 0.f ? lA : 0.2f * lA;
            lB = lB > 0.f ? lB : 0.2f * lB;
            float wA = __expf(lA);
            float wB = (eB < s1) ? __expf(lB) : 0.f;
            den_part += wA + wB;
            v2f wA2 = {wA, wA}, wB2 = {wB, wB};
            accL += wA2 * fp8x2f<false>(hA);
            accH += wA2 * fp8x2f<true>(hA);
            accL += wB2 * fp8x2f<false>(hB);
            accH += wB2 * fp8x2f<true>(hB);
            i += 8;
        }
        if (rem & 4) {  // 4 edges
            int eA = base + i + g;
            int xA = eA < s1 ? eA : s1 - 1;
            int cA = col[xA];
            const uchar* rA = rec1 + (((uint)cA) << 7);
            uint hA = *(const uint*)(rA + co);
            float lA = *(const float*)(rA + ao) + a_dh;
            lA = lA > 0.f ? lA : 0.2f * lA;
            float wA = (eA < s1) ? __expf(lA) : 0.f;
            den_part += wA;
            v2f wA2 = {wA, wA};
            accL += wA2 * fp8x2f<false>(hA);
            accH += wA2 * fp8x2f<true>(hA);
        }
    }
    float a0 = accL.x, a1 = accL.y, a2 = accH.x, a3 = accH.y;
    a0 += __shfl_xor(a0, 16); a0 += __shfl_xor(a0, 32);
    a1 += __shfl_xor(a1, 16); a1 += __shfl_xor(a1, 32);
    a2 += __shfl_xor(a2, 16); a2 += __shfl_xor(a2, 32);
    a3 += __shfl_xor(a3, 16); a3 += __shfl_xor(a3, 32);
    den_part += __shfl_xor(den_part, 16);
    den_part += __shfl_xor(den_part, 32);   // per-lane den for head hh
    if (lane < 16) {
        float invd = 1.f / (den_part * S1);
        h4v o;
        o[0] = (_Float16)(a0 * invd);
        o[1] = (_Float16)(a1 * invd);
        o[2] = (_Float16)(a2 * invd);
        o[3] = (_Float16)(a3 * invd);
        *(h4v*)(x1pre + (size_t)node * 64 + co) = o;
    }
}

// ---- edge2: wave/node; fp8 gathers; quad-distributed weights + ds_swizzle bcast ----
// Each lane computes the weight for ONE of its group's 4 in-flight edges
// (quad q = k8>>2 handles edge i + q*4 + g), then 4 BitMode swizzles broadcast
// wA..wD to all 16 lanes (and to both halves of the wave, since the swizzle
// and-mask 0x10 keeps the group bit).
__global__ __launch_bounds__(256) void k_edge2(const uchar* __restrict__ h2f8,
                                               const float* __restrict__ al2s,
                                               const float* __restrict__ al2d,
                                               const int* __restrict__ row_ptr,
                                               const int* __restrict__ col,
                                               _Float16* __restrict__ x2, int N) {
    int node = blockIdx.x * 4 + (threadIdx.x >> 6);
    if (node >= N) return;
    const int lane = threadIdx.x & 63;
    const int g = lane >> 4;    // edge group 0..3
    const int k8 = lane & 15;   // channel oct (ch 8k8..8k8+7 of 128)
    const int q = k8 >> 2;      // weight quad 0..3
    const uint co = (uint)(k8 * 8);
    const float a_d = al2d[node];
    const int s0 = row_ptr[node], s1 = row_ptr[node + 1];
    v2f acc0 = {0.f, 0.f}, acc1 = {0.f, 0.f}, acc2 = {0.f, 0.f}, acc3 = {0.f, 0.f};
    float den_part = 0.f;
    // BitMode offset = (xor<<10)|(or<<5)|and. Broadcast lane (and=0x10, or=K):
    // dst lane reads lane (lane&0x10)|K within each 32-lane half.
    for (int base = s0; base < s1; base += 64) {
        int cnt = s1 - base; if (cnt > 64) cnt = 64;
        int cntR = (cnt + 3) & ~3;
        int i = 0;
        for (; i + 16 <= cntR; i += 16) {
            int eA = base + i + g, eB = eA + 4, eC = eA + 8, eD = eA + 12;
            int xD = eD < s1 ? eD : s1 - 1;
            int cA = col[eA], cB = col[eB], cC = col[eC], cD = col[xD];
            uint2 hA = *(const uint2*)(h2f8 + ((((uint)cA) << 7) | co));
            uint2 hB = *(const uint2*)(h2f8 + ((((uint)cB) << 7) | co));
            uint2 hC = *(const uint2*)(h2f8 + ((((uint)cC) << 7) | co));
            uint2 hD = *(const uint2*)(h2f8 + ((((uint)cD) << 7) | co));
            // quad-distributed weight: lane's q-th edge only
            int eQ = eA + q * 4;                 // i + q*4 + g
            int xQ = eQ < s1 ? eQ : s1 - 1;      // only q==3 can run past
            int cQ = col[xQ];
            float lQ = al2s[(uint)cQ] + a_d;
            lQ = lQ > 0.f ? lQ : 0.2f * lQ;
            float wQ = (eQ < s1) ? __expf(lQ) : 0.f;
            // broadcast from k8=0,4,8,12 (and=0x10 keeps group bit per half)
            float wA = swz<0x0010>(wQ);          // or=0  -> k8=0  (q=0)
            float wB = swz<0x0090>(wQ);          // or=4  -> k8=4  (q=1)
            float wC = swz<0x0110>(wQ);          // or=8  -> k8=8  (q=2)
            float wD = swz<0x0190>(wQ);          // or=12 -> k8=12 (q=3)
            den_part += wA + wB + wC + wD;
            v2f wA2 = {wA, wA}, wB2 = {wB, wB}, wC2 = {wC, wC}, wD2 = {wD, wD};
            acc0 += wA2 * fp8x2f<false>(hA.x);
            acc1 += wA2 * fp8x2f<true>(hA.x);
            acc2 += wA2 * fp8x2f<false>(hA.y);
            acc3 += wA2 * fp8x2f<true>(hA.y);
            acc0 += wB2 * fp8x2f<false>(hB.x);
            acc1 += wB2 * fp8x2f<true>(hB.x);
            acc2 += wB2 * fp8x2f<false>(hB.y);
            acc3 += wB2 * fp8x2f<true>(hB.y);
            acc0 += wC2 * fp8x2f<false>(hC.x);
            acc1 += wC2 * fp8x2f<true>(hC.x);
            acc2 += wC2 * fp8x2f<false>(hC.y);
            acc3 += wC2 * fp8x2f<true>(hC.y);
            acc0 += wD2 * fp8x2f<false>(hD.x);
            acc1 += wD2 * fp8x2f<true>(hD.x);
            acc2 += wD2 * fp8x2f<false>(hD.y);
            acc3 += wD2 * fp8x2f<true>(hD.y);
        }
        int rem = cntR - i;
        if (rem & 8) {   // 8 edges: halves of the group compute wA / wB
            int eA = base + i + g, eB = eA + 4;
            int xB = eB < s1 ? eB : s1 - 1;
            int cA = col[eA], cB = col[xB];
            uint2 hA = *(const uint2*)(h2f8 + ((((uint)cA) << 7) | co));
            uint2 hB = *(const uint2*)(h2f8 + ((((uint)cB) << 7) | co));
            int eH = (k8 < 8) ? eA : eB;
            int xH = eH < s1 ? eH : s1 - 1;
            int cH = col[xH];
            float lH = al2s[(uint)cH] + a_d;
            lH = lH > 0.f ? lH : 0.2f * lH;
            float wH = (eH < s1) ? __expf(lH) : 0.f;
            float wA = swz<0x0010>(wH);          // k8=0 computed wA
            float wB = swz<0x0110>(wH);          // k8=8 computed wB
            den_part += wA + wB;
            v2f wA2 = {wA, wA}, wB2 = {wB, wB};
            acc0 += wA2 * fp8x2f<false>(hA.x);
            acc1 += wA2 * fp8x2f<true>(hA.x);
            acc2 += wA2 * fp8x2f<false>(hA.y);
            acc3 += wA2 * fp8x2f<true>(hA.y);
            acc0 += wB2 * fp8x2f<false>(hB.x);
            acc1 += wB2 * fp8x2f<true>(hB.x);
            acc2 += wB2 * fp8x2f<false>(hB.y);
            acc3 += wB2 * fp8x2f<true>(hB.y);
            i += 8;
        }
        if (rem & 4) {   // 4 edges: single exp, keep redundant (cheap)
            int eA = base + i + g;
            int xA = eA < s1 ? eA : s1 - 1;
            int cA = col[xA];
            uint2 hA = *(const uint2*)(h2f8 + ((((uint)cA) << 7) | co));
            float lA = al2s[(uint)cA] + a_d;
            lA = lA > 0.f ? lA : 0.2f * lA;
            float wA = (eA < s1) ? __expf(lA) : 0.f;
            den_part += wA;
            v2f wA2 = {wA, wA};
            acc0 += wA2 * fp8x2f<false>(hA.x);
            acc1 += wA2 * fp8x2f<true>(hA.x);
            acc2 += wA2 * fp8x2f<false>(hA.y);
            acc3 += wA2 * fp8x2f<true>(hA.y);
        }
    }
    den_part += __shfl_xor(den_part, 16);
    den_part += __shfl_xor(den_part, 32);
    float r0 = acc0.x, r1 = acc0.y, r2 = acc1.x, r3 = acc1.y;
    float r4 = acc2.x, r5 = acc2.y, r6 = acc3.x, r7 = acc3.y;
    r0 += __shfl_xor(r0, 16); r0 += __shfl_xor(r0, 32);
    r1 += __shfl_xor(r1, 16); r1 += __shfl_xor(r1, 32);
    r2 += __shfl_xor(r2, 16); r2 += __shfl_xor(r2, 32);
    r3 += __shfl_xor(r3, 16); r3 += __shfl_xor(r3, 32);
    r4 += __shfl_xor(r4, 16); r4 += __shfl_xor(r4, 32);
    r5 += __shfl_xor(r5, 16); r5 += __shfl_xor(r5, 32);
    r6 += __shfl_xor(r6, 16); r6 += __shfl_xor(r6, 32);
    r7 += __shfl_xor(r7, 16); r7 += __shfl_xor(r7, 32);
    if (lane < 16) {
        float invd = 1.f / (den_part * S2);
        h8v o;
        o[0] = (_Float16)(r0 * invd);
        o[1] = (_Float16)(r1 * invd);
        o[2] = (_Float16)(r2 * invd);
        o[3] = (_Float16)(r3 * invd);
        o[4] = (_Float16)(r4 * invd);
        o[5] = (_Float16)(r5 * invd);
        o[6] = (_Float16)(r6 * invd);
        o[7] = (_Float16)(r7 * invd);
        *(h8v*)(x2 + (size_t)node * 128 + co) = o;
    }
}

// ---- k_poolfc: one block per graph; batch sorted -> binary-search node range,
// mean-pool in registers (no atomics, no memset), then wave 0 does FC+logsoftmax.
__global__ __launch_bounds__(128) void k_poolfc(const _Float16* __restrict__ x2,
                                                const int* __restrict__ batch,
                                                const float* __restrict__ b2,
                                                const float* __restrict__ fcw,
                                                const float* __restrict__ fcb,
                                                float* __restrict__ out,
                                                int N, int G) {
    __shared__ float sp[128];
    const int g = blockIdx.x;
    const int t = threadIdx.x;
    int lo = 0, hi = N;
    while (lo < hi) { int m = (lo + hi) >> 1; if (batch[m] < g) lo = m + 1; else hi = m; }
    const int s = lo;
    hi = N;
    while (lo < hi) { int m = (lo + hi) >> 1; if (batch[m] < g + 1) lo = m + 1; else hi = m; }
    const int e = lo;
    float a0 = 0.f, a1 = 0.f, a2 = 0.f, a3 = 0.f;
    int n = s;
    for (; n + 4 <= e; n += 4) {
        a0 += (float)x2[(size_t)(n + 0) * 128 + t];
        a1 += (float)x2[(size_t)(n + 1) * 128 + t];
        a2 += (float)x2[(size_t)(n + 2) * 128 + t];
        a3 += (float)x2[(size_t)(n + 3) * 128 + t];
    }
    for (; n < e; ++n) a0 += (float)x2[(size_t)n * 128 + t];
    float inv = 1.f / fmaxf((float)(e - s), 1.f);
    sp[t] = (a0 + a1 + a2 + a3) * inv + b2[t];
    __syncthreads();
    if (t < 64) {
        int c = t;
        float2 p = ((const float2*)sp)[c];
        float l[10];
#pragma unroll
        for (int j = 0; j < 10; ++j)
            l[j] = p.x * fcw[(2 * c) * 10 + j] + p.y * fcw[(2 * c + 1) * 10 + j];
#pragma unroll
        for (int j = 0; j < 10; ++j)
            for (int off = 1; off < 64; off <<= 1) l[j] += __shfl_xor(l[j], off);
        if (c == 0) {
            float lj[10];
            float m = -1e30f;
#pragma unroll
            for (int j = 0; j < 10; ++j) {
                lj[j] = l[j] + fcb[j];
                m = fmaxf(m, lj[j]);
            }
            float sde = 0.f;
#pragma unroll
            for (int j = 0; j < 10; ++j) sde += expf(lj[j] - m);
            float ls = logf(sde);
#pragma unroll
            for (int j = 0; j < 10; ++j) out[(size_t)g * 10 + j] = lj[j] - m - ls;
        }
    }
}

extern "C" void kernel_launch(void* const* d_in, const int* in_sizes, int n_in,
                              void* d_out, int out_size, void* d_ws, size_t ws_size,
                              hipStream_t stream) {
    const float* x     = (const float*)d_in[0];
    const int*   ei    = (const int*)d_in[1];
    const int*   batch = (const int*)d_in[2];
    const float* W1    = (const float*)d_in[3];
    const float* as1   = (const float*)d_in[4];
    const float* ad1   = (const float*)d_in[5];
    const float* b1    = (const float*)d_in[6];
    const float* W2    = (const float*)d_in[7];
    const float* as2   = (const float*)d_in[8];
    const float* ad2   = (const float*)d_in[9];
    const float* b2    = (const float*)d_in[10];
    const float* fcw   = (const float*)d_in[11];
    const float* fcb   = (const float*)d_in[12];
    float* out = (float*)d_out;

    const int N = in_sizes[0] / 128;
    const int E = in_sizes[1] / 2;
    const int G = out_size / 10;
    const int* srcp = ei;
    const int* dstp = ei + E;

    // workspace (float units):
    //   [0,32N)     rec1 (N x 128B packed) -- dead after k_edge1
    //   [32N,64N)   x1pre (fp16 N*64)      -- dead after k_gemm2
    //   [0,64N)     x2 (fp16 N*128) -- aliases dead rec1/x1pre
    //   [128N,160N) h2f8 (N*128 fp8)
    //   [192N,193N) al2s  [193N,194N) al2d
    //   [194N,...)  int region (ebuf, counts, btot, bbase, row_ptr, col)
    float* wf = (float*)d_ws;
    uchar*    rec1  = (uchar*)wf;
    _Float16* x1pre = (_Float16*)(wf + (size_t)N * 32);
    _Float16* x2    = (_Float16*)wf;
    uchar*    h2f8  = (uchar*)(wf + (size_t)N * 128);
    float* al2s_  = wf + (size_t)N * 192;
    float* al2d_  = wf + (size_t)N * 193;

    const int NB = (N + 127) >> 7;      // 782 buckets (requires NB <= 784)
    const int C  = 256;                 // histogram/scatter blocks (longer runs)
    const int CH = (E + C - 1) / C;     // edges per block

    int* ib = (int*)(((uintptr_t)(wf + (size_t)N * 194) + 15) & ~(uintptr_t)15);
    int* ebuf    = ib;                              // [E] packed src|((dst&127)<<25)
    int* counts  = ib + (size_t)E;                  // [C*NB]
    int* btot    = counts + (size_t)C * NB;         // [NB]
    int* bbase   = btot + NB;                       // [NB+1]
    int* row_ptr = bbase + NB + 1;                  // [N+1]
    int* col     = row_ptr + N + 1;                 // [E+N]

    const int nb64 = (N + 63) / 64;
    const int nb4  = (N + 3) / 4;

    k_g1h<<<nb64 + C, 256, 0, stream>>>(x, W1, as1, ad1, rec1, dstp, counts,
                                        N, E, CH, NB, nb64);
    k_bscan<<<NB, 256, 0, stream>>>(counts, btot, C, NB);
    k_bucket<<<C, 256, 0, stream>>>(srcp, dstp, counts, btot, bbase, ebuf, E, CH, NB);
    k_csr<<<NB, 256, 0, stream>>>(bbase, ebuf, row_ptr, col, N, E);
    k_edge1<<<nb4, 256, 0, stream>>>(rec1, row_ptr, col, x1pre, N);
    k_gemm2<<<nb64, 256, 0, stream>>>(x1pre, W2, b1, as2, ad2, h2f8, al2s_, al2d_, N);
    k_edge2<<<nb4, 256, 0, stream>>>(h2f8, al2s_, al2d_, row_ptr, col, x2, N);
    k_poolfc<<<G, 128, 0, stream>>>(x2, batch, b2, fcw, fcb, out, N, G);
}